// Round 15
// baseline (177.949 us; speedup 1.0000x reference)
//
#include <hip/hip_runtime.h>

#define B_ 2
#define C_ 256
#define S_ 2304
#define DH_ 64
#define O3_ 1536
#define INNER_ 512
#define LOGSMAX 4.605170185988092f
#define LOG2E 1.4426950408889634f

typedef __attribute__((ext_vector_type(8))) short short8;
typedef __attribute__((ext_vector_type(4))) float f32x4;
typedef __attribute__((ext_vector_type(16))) float f32x16;
typedef __attribute__((ext_vector_type(4))) unsigned short us4;
typedef __attribute__((ext_vector_type(4))) unsigned u32x4;
typedef __bf16 bf16x8 __attribute__((ext_vector_type(8)));

__device__ __forceinline__ unsigned short f2bf(float f) {
  unsigned u = __builtin_bit_cast(unsigned, f);
  u += 0x7FFFu + ((u >> 16) & 1u);
  return (unsigned short)(u >> 16);
}
__device__ __forceinline__ float bf2f(unsigned short h) {
  return __builtin_bit_cast(float, (unsigned)h << 16);
}
__device__ __forceinline__ bf16x8 as_bf(short8 v) {
  return __builtin_bit_cast(bf16x8, v);
}
__device__ __forceinline__ float fexp2(float x) {
#if __has_builtin(__builtin_amdgcn_exp2f)
  return __builtin_amdgcn_exp2f(x);
#else
  return __expf(x * 0.6931471805599453f);
#endif
}
__device__ __forceinline__ float frcp(float x) {
#if __has_builtin(__builtin_amdgcn_rcpf)
  return __builtin_amdgcn_rcpf(x);
#else
  return 1.f / x;
#endif
}
// pack hi16 of two fp32 bit-patterns: (hi16(b)<<16)|hi16(a) — 1 v_perm_b32
__device__ __forceinline__ unsigned pack_hi16(unsigned b, unsigned a) {
  return __builtin_amdgcn_perm(b, a, 0x07060302u);
}
// half-up bf16 pair pack: dword low = bf16(a), high = bf16(b)
__device__ __forceinline__ unsigned pk2(float a, float b) {
  unsigned ua = __builtin_bit_cast(unsigned, a) + 0x8000u;
  unsigned ub = __builtin_bit_cast(unsigned, b) + 0x8000u;
  return pack_hi16(ub, ua);
}

// ---------------- K0: fused prep: x transpose + both weight converts ----------------
__global__ __launch_bounds__(256) void k_prep(const float* __restrict__ x,
                                              const float* __restrict__ w_in,
                                              const float* __restrict__ w_pw,
                                              unsigned short* __restrict__ xT,
                                              unsigned short* __restrict__ w_inb,
                                              unsigned short* __restrict__ w_pwb) {
  __shared__ float tile[64][65];
  int blk = blockIdx.x;
  int t = threadIdx.x;
  if (blk < 288) {  // transpose x [b][c][p] -> xT [b][p][c] bf16
    int p0 = (blk % 36) * 64, c0 = ((blk / 36) % 4) * 64, b = blk / 144;
    const float* xb = x + (size_t)b * C_ * S_;
#pragma unroll
    for (int i = 0; i < 16; i++) {
      int c = i * 4 + (t >> 6);
      int p = t & 63;
      tile[c][p] = xb[(size_t)(c0 + c) * S_ + p0 + p];
    }
    __syncthreads();
    unsigned short* xTb = xT + (size_t)b * S_ * C_;
#pragma unroll
    for (int i = 0; i < 16; i++) {
      int p = i * 4 + (t >> 6);
      int c = t & 63;
      xTb[(size_t)(p0 + p) * C_ + c0 + c] = f2bf(tile[c][p]);
    }
  } else if (blk < 288 + 1536) {
    int i = (blk - 288) * 256 + t;
    w_inb[i] = f2bf(w_in[i]);
  } else {
    int i = (blk - 1824) * 256 + t;
    w_pwb[i] = f2bf(w_pw[i]);
  }
}

// ---------------- K1: proj_in GEMM with fused bias + l2norm + scale epilogue ----------------
// 64x128 tile; M-tile 64 == one (head, q/k/v-seg) channel group.
// Writes qn/kn fp8 [bh][p][64] (scale*log2e folded into q), vT bf16 [bh][d][p] via LDS retile.
__global__ __launch_bounds__(256) void k_gemm_qkv(const unsigned short* __restrict__ A,
                                                  const unsigned short* __restrict__ BT,
                                                  const float* __restrict__ b_in,
                                                  const float* __restrict__ ss,
                                                  unsigned char* __restrict__ qn,
                                                  unsigned char* __restrict__ kn,
                                                  unsigned short* __restrict__ vT) {
  __shared__ __align__(16) unsigned short smem[64 * 72 + 128 * 72];
  unsigned short (*As)[72] = (unsigned short(*)[72])smem;
  unsigned short (*Bs)[72] = (unsigned short(*)[72])(smem + 64 * 72);
  int t = threadIdx.x;
  int lane = t & 63, wv = t >> 6;
  int quad = lane >> 4, r15 = lane & 15;
  int by = blockIdx.y;
  int m0 = by * 64, n0 = blockIdx.x * 128;
  int b = blockIdx.z;
  const unsigned short* BTb = BT + (size_t)b * S_ * C_;

  f32x4 acc[4][2] = {};

  int srA = t >> 2, scA = (t & 3) * 16;
  int srB = t >> 1, scB = (t & 1) * 32;
  const unsigned short* ag = A + (size_t)(m0 + srA) * C_ + scA;
  const unsigned short* bg = BTb + (size_t)(n0 + srB) * C_ + scB;

  for (int k0 = 0; k0 < C_; k0 += 64) {
    short8 a0 = *(const short8*)(ag + k0);
    short8 a1 = *(const short8*)(ag + k0 + 8);
    short8 b0 = *(const short8*)(bg + k0);
    short8 b1 = *(const short8*)(bg + k0 + 8);
    short8 b2 = *(const short8*)(bg + k0 + 16);
    short8 b3 = *(const short8*)(bg + k0 + 24);
    __syncthreads();
    *(short8*)&As[srA][scA] = a0;
    *(short8*)&As[srA][scA + 8] = a1;
    *(short8*)&Bs[srB][scB] = b0;
    *(short8*)&Bs[srB][scB + 8] = b1;
    *(short8*)&Bs[srB][scB + 16] = b2;
    *(short8*)&Bs[srB][scB + 24] = b3;
    __syncthreads();
#pragma unroll
    for (int ks = 0; ks < 2; ks++) {
      short8 af[4], bfr[2];
#pragma unroll
      for (int i = 0; i < 4; i++) af[i] = *(const short8*)&As[i * 16 + r15][ks * 32 + quad * 8];
#pragma unroll
      for (int j = 0; j < 2; j++) bfr[j] = *(const short8*)&Bs[wv * 32 + j * 16 + r15][ks * 32 + quad * 8];
#pragma unroll
      for (int i = 0; i < 4; i++)
#pragma unroll
        for (int j = 0; j < 2; j++)
          acc[i][j] = __builtin_amdgcn_mfma_f32_16x16x32_bf16(as_bf(af[i]), as_bf(bfr[j]), acc[i][j], 0, 0, 0);
    }
  }

  // epilogue: bias add, per-position l2norm (q/k) -> fp8; v -> vT bf16 [d][p] via LDS
  int h = by / 3, seg = by - h * 3;
  int bh = b * 8 + h;
  f32x4 bi[4];
#pragma unroll
  for (int i = 0; i < 4; i++) bi[i] = *(const f32x4*)&b_in[m0 + i * 16 + quad * 4];
  float bv[4][2][4];
  float ssq0 = 0.f, ssq1 = 0.f;
#pragma unroll
  for (int i = 0; i < 4; i++)
#pragma unroll
    for (int rr = 0; rr < 4; rr++) {
      float v0 = acc[i][0][rr] + bi[i][rr];
      float v1 = acc[i][1][rr] + bi[i][rr];
      bv[i][0][rr] = v0;
      bv[i][1][rr] = v1;
      ssq0 += v0 * v0;
      ssq1 += v1 * v1;
    }
  if (seg < 2) {
    float sc = (seg == 0) ? __expf(fminf(ss[h], LOGSMAX)) * LOG2E : 1.f;
    ssq0 += __shfl_xor(ssq0, 16);
    ssq0 += __shfl_xor(ssq0, 32);
    ssq1 += __shfl_xor(ssq1, 16);
    ssq1 += __shfl_xor(ssq1, 32);
    float inv0 = sc / fmaxf(sqrtf(ssq0), 1e-12f);
    float inv1 = sc / fmaxf(sqrtf(ssq1), 1e-12f);
    unsigned char* dst = (seg == 0 ? qn : kn) + (size_t)bh * S_ * DH_;
#pragma unroll
    for (int i = 0; i < 4; i++)
#pragma unroll
      for (int j = 0; j < 2; j++) {
        float iv = j ? inv1 : inv0;
        int pk = __builtin_amdgcn_cvt_pk_fp8_f32(bv[i][j][0] * iv, bv[i][j][1] * iv, 0, false);
        pk = __builtin_amdgcn_cvt_pk_fp8_f32(bv[i][j][2] * iv, bv[i][j][3] * iv, pk, true);
        int p = n0 + wv * 32 + j * 16 + r15;
        *(int*)&dst[(size_t)p * DH_ + i * 16 + quad * 4] = pk;
      }
  } else {
    // retile v through LDS: [d][p] tile (stride 132), then coalesced 16B stores
    __syncthreads();
    unsigned short* vt = smem;
#pragma unroll
    for (int i = 0; i < 4; i++)
#pragma unroll
      for (int j = 0; j < 2; j++) {
        int pcol = wv * 32 + j * 16 + r15;
#pragma unroll
        for (int rr = 0; rr < 4; rr++) {
          int d = i * 16 + quad * 4 + rr;
          vt[d * 132 + pcol] = f2bf(bv[i][j][rr]);
        }
      }
    __syncthreads();
    unsigned short* dst = vT + (size_t)bh * DH_ * S_;
    int dr = t >> 2, pc = (t & 3) * 32;
#pragma unroll
    for (int s2 = 0; s2 < 4; s2++) {
      short8 v8 = *(const short8*)&vt[dr * 132 + pc + s2 * 8];
      *(short8*)&dst[(size_t)dr * S_ + n0 + pc + s2 * 8] = v8;
    }
  }
}

// ---------------- K5: pw GEMM, 64x64 tile, 2 waves, bf16 output ----------------
__global__ __launch_bounds__(128) void k_gemm2(const unsigned short* __restrict__ A,
                                               const unsigned short* __restrict__ BT,
                                               unsigned short* __restrict__ outp,
                                               int M, int N, int K) {
  __shared__ __align__(16) unsigned short As[64][72];
  __shared__ __align__(16) unsigned short Bs[64][72];
  int t = threadIdx.x;
  int lane = t & 63, wv = t >> 6;
  int quad = lane >> 4, r15 = lane & 15;
  int m0 = blockIdx.y * 64, n0 = blockIdx.x * 64;
  int b = blockIdx.z;
  const unsigned short* BTb = BT + (size_t)b * N * K;

  f32x4 acc[4][2] = {};

  int sr = t >> 1, sc = (t & 1) * 32;
  const unsigned short* ag = A + (size_t)(m0 + sr) * K + sc;
  const unsigned short* bg = BTb + (size_t)(n0 + sr) * K + sc;

  for (int k0 = 0; k0 < K; k0 += 64) {
    short8 a0 = *(const short8*)(ag + k0);
    short8 a1 = *(const short8*)(ag + k0 + 8);
    short8 a2 = *(const short8*)(ag + k0 + 16);
    short8 a3 = *(const short8*)(ag + k0 + 24);
    short8 b0 = *(const short8*)(bg + k0);
    short8 b1 = *(const short8*)(bg + k0 + 8);
    short8 b2 = *(const short8*)(bg + k0 + 16);
    short8 b3 = *(const short8*)(bg + k0 + 24);
    __syncthreads();
    *(short8*)&As[sr][sc] = a0;
    *(short8*)&As[sr][sc + 8] = a1;
    *(short8*)&As[sr][sc + 16] = a2;
    *(short8*)&As[sr][sc + 24] = a3;
    *(short8*)&Bs[sr][sc] = b0;
    *(short8*)&Bs[sr][sc + 8] = b1;
    *(short8*)&Bs[sr][sc + 16] = b2;
    *(short8*)&Bs[sr][sc + 24] = b3;
    __syncthreads();
#pragma unroll
    for (int ks = 0; ks < 2; ks++) {
      short8 af[4], bfr[2];
#pragma unroll
      for (int i = 0; i < 4; i++) af[i] = *(const short8*)&As[i * 16 + r15][ks * 32 + quad * 8];
#pragma unroll
      for (int j = 0; j < 2; j++) bfr[j] = *(const short8*)&Bs[wv * 32 + j * 16 + r15][ks * 32 + quad * 8];
#pragma unroll
      for (int i = 0; i < 4; i++)
#pragma unroll
        for (int j = 0; j < 2; j++)
          acc[i][j] = __builtin_amdgcn_mfma_f32_16x16x32_bf16(as_bf(af[i]), as_bf(bfr[j]), acc[i][j], 0, 0, 0);
    }
  }
  unsigned short* Cb = outp + (size_t)b * M * N;
#pragma unroll
  for (int i = 0; i < 4; i++)
#pragma unroll
    for (int j = 0; j < 2; j++)
#pragma unroll
      for (int rr = 0; rr < 4; rr++) {
        int row = m0 + i * 16 + quad * 4 + rr;
        int col = n0 + wv * 32 + j * 16 + r15;
        Cb[(size_t)row * N + col] = f2bf(acc[i][j][rr]);
      }
}

// ---------------- K3: hybrid attention, 2 query-chunks/wave, frag-shared MFMA ----------------
// Q/K fp8 (S^T MFMA), P/V bf16 (O MFMA). 4 waves x 64q (2x32), split-K x4.
// Key-halves processed sequentially to cap live score registers.
// Grid (bh, qtile, split): bh fastest -> XCD = bh%8 pinned.
__global__ __launch_bounds__(256) void k_attn(const unsigned char* __restrict__ qn,
                                              const unsigned char* __restrict__ kn,
                                              const unsigned short* __restrict__ vT,
                                              const float* __restrict__ ss,
                                              unsigned short* __restrict__ attnp,
                                              float* __restrict__ lp) {
  __shared__ __align__(16) unsigned char Ks[64][72];       // [key][d] fp8
  __shared__ __align__(16) unsigned short Vs[64][72];      // [d][key] bf16
  int t = threadIdx.x;
  int w = t >> 6;
  int lane = t & 63;
  int l31 = lane & 31, hi = lane >> 5;
  int bh = blockIdx.x;
  int q0A = blockIdx.y * 256 + w * 32;
  int q0B = q0A + 128;
  int split = blockIdx.z;
  int ktbase = split * 9;
  const unsigned char* qb = qn + (size_t)bh * S_ * DH_;
  const unsigned char* kb = kn + (size_t)bh * S_ * DH_;
  const unsigned short* vb = vT + (size_t)bh * DH_ * S_;
  float shift2 = __expf(fminf(ss[bh & 7], LOGSMAX)) * LOG2E;  // |s'| <= shift2

  // Q as fp8 B-fragments: n=query=l31, k(d) = ks*16 + hi*8 + j
  const unsigned char* qrowA = qb + (size_t)(q0A + l31) * DH_ + hi * 8;
  const unsigned char* qrowB = qb + (size_t)(q0B + l31) * DH_ + hi * 8;
  long qfA[4], qfB[4];
#pragma unroll
  for (int ks = 0; ks < 4; ks++) {
    qfA[ks] = *(const long*)(qrowA + ks * 16);
    qfB[ks] = *(const long*)(qrowB + ks * 16);
  }

  const f32x16 z16 = {};
  f32x16 OA0 = z16, OA1 = z16, OB0 = z16, OB1 = z16;
  float lA = 0.f, lB = 0.f;

  // staging: K 64key x 64B fp8 (16B/thread), V 64d x 64key bf16 (32B/thread)
  int srow = t >> 2;
  int scolK = (t & 3) * 16;
  int scolV = (t & 3) * 16;
  const unsigned char* kg = kb + ((size_t)(ktbase * 64) + srow) * DH_ + scolK;
  const unsigned short* vg = vb + (size_t)srow * S_ + ktbase * 64 + scolV;

  uint4 kr = *(const uint4*)kg;
  short8 vr0 = *(const short8*)vg;
  short8 vr1 = *(const short8*)(vg + 8);

  for (int i = 0; i < 9; i++) {
    __syncthreads();
    *(uint4*)&Ks[srow][scolK] = kr;
    *(short8*)&Vs[srow][scolV] = vr0;
    *(short8*)&Vs[srow][scolV + 8] = vr1;
    __syncthreads();
    if (i < 8) {  // prefetch next tile
      kr = *(const uint4*)(kg + (size_t)(i + 1) * 64 * DH_);
      vr0 = *(const short8*)(vg + (i + 1) * 64);
      vr1 = *(const short8*)(vg + (i + 1) * 64 + 8);
    }
    // key-half mt: keys mt*32..mt*32+31
#pragma unroll
    for (int mt = 0; mt < 2; mt++) {
      // S^T = K Q^T for both chunks, shared K frag
      f32x16 sA, sB;
      {
        long a = *(const long*)&Ks[mt * 32 + l31][hi * 8];
        sA = __builtin_amdgcn_mfma_f32_32x32x16_fp8_fp8(a, qfA[0], z16, 0, 0, 0);
        sB = __builtin_amdgcn_mfma_f32_32x32x16_fp8_fp8(a, qfB[0], z16, 0, 0, 0);
      }
#pragma unroll
      for (int ks = 1; ks < 4; ks++) {
        long a = *(const long*)&Ks[mt * 32 + l31][ks * 16 + hi * 8];
        sA = __builtin_amdgcn_mfma_f32_32x32x16_fp8_fp8(a, qfA[ks], sA, 0, 0, 0);
        sB = __builtin_amdgcn_mfma_f32_32x32x16_fp8_fp8(a, qfB[ks], sB, 0, 0, 0);
      }
      // softmax numerators for both chunks
      unsigned pkA[8], pkB[8];
      float lsA = 0.f, lsB = 0.f;
#pragma unroll
      for (int g2 = 0; g2 < 4; g2++) {
        float a0 = fexp2(sA[g2 * 4 + 0] - shift2);
        float a1 = fexp2(sA[g2 * 4 + 1] - shift2);
        float a2 = fexp2(sA[g2 * 4 + 2] - shift2);
        float a3 = fexp2(sA[g2 * 4 + 3] - shift2);
        lsA += (a0 + a1) + (a2 + a3);
        pkA[2 * g2] = pk2(a0, a1);
        pkA[2 * g2 + 1] = pk2(a2, a3);
        float b0 = fexp2(sB[g2 * 4 + 0] - shift2);
        float b1 = fexp2(sB[g2 * 4 + 1] - shift2);
        float b2 = fexp2(sB[g2 * 4 + 2] - shift2);
        float b3 = fexp2(sB[g2 * 4 + 3] - shift2);
        lsB += (b0 + b1) + (b2 + b3);
        pkB[2 * g2] = pk2(b0, b1);
        pkB[2 * g2 + 1] = pk2(b2, b3);
      }
      lA += lsA;
      lB += lsB;
      // relayout via shfl_xor(32), PV with shared V frags
#pragma unroll
      for (int half = 0; half < 2; half++) {
        int gb = half * 4;
        unsigned yaA = hi ? pkA[gb + 0] : pkA[gb + 2];
        unsigned ybA = hi ? pkA[gb + 1] : pkA[gb + 3];
        unsigned raA = __shfl_xor(yaA, 32);
        unsigned rbA = __shfl_xor(ybA, 32);
        u32x4 fdA;
        fdA[0] = hi ? raA : pkA[gb + 0];
        fdA[1] = hi ? rbA : pkA[gb + 1];
        fdA[2] = hi ? pkA[gb + 2] : raA;
        fdA[3] = hi ? pkA[gb + 3] : rbA;
        short8 pbA = __builtin_bit_cast(short8, fdA);
        unsigned yaB = hi ? pkB[gb + 0] : pkB[gb + 2];
        unsigned ybB = hi ? pkB[gb + 1] : pkB[gb + 3];
        unsigned raB = __shfl_xor(yaB, 32);
        unsigned rbB = __shfl_xor(ybB, 32);
        u32x4 fdB;
        fdB[0] = hi ? raB : pkB[gb + 0];
        fdB[1] = hi ? rbB : pkB[gb + 1];
        fdB[2] = hi ? pkB[gb + 2] : raB;
        fdB[3] = hi ? pkB[gb + 3] : rbB;
        short8 pbB = __builtin_bit_cast(short8, fdB);
        int ks = mt * 2 + half;
        short8 va0 = *(const short8*)&Vs[l31][ks * 16 + hi * 8];
        short8 va1 = *(const short8*)&Vs[32 + l31][ks * 16 + hi * 8];
        OA0 = __builtin_amdgcn_mfma_f32_32x32x16_bf16(as_bf(va0), as_bf(pbA), OA0, 0, 0, 0);
        OA1 = __builtin_amdgcn_mfma_f32_32x32x16_bf16(as_bf(va1), as_bf(pbA), OA1, 0, 0, 0);
        OB0 = __builtin_amdgcn_mfma_f32_32x32x16_bf16(as_bf(va0), as_bf(pbB), OB0, 0, 0, 0);
        OB1 = __builtin_amdgcn_mfma_f32_32x32x16_bf16(as_bf(va1), as_bf(pbB), OB1, 0, 0, 0);
      }
    }
  }
  float lAt = lA + __shfl_xor(lA, 32);
  float lBt = lB + __shfl_xor(lB, 32);
  size_t lbase = ((size_t)(split * 16 + bh)) * S_;
  if (hi == 0) {
    lp[lbase + q0A + l31] = lAt;
    lp[lbase + q0B + l31] = lBt;
  }
  unsigned short* orowA = attnp + (lbase + q0A + l31) * DH_;
  unsigned short* orowB = attnp + (lbase + q0B + l31) * DH_;
#pragma unroll
  for (int mt = 0; mt < 2; mt++) {
    const f32x16& OA = mt ? OA1 : OA0;
    const f32x16& OB = mt ? OB1 : OB0;
#pragma unroll
    for (int g = 0; g < 4; g++) {
      us4 oa = {f2bf(OA[g * 4 + 0]), f2bf(OA[g * 4 + 1]), f2bf(OA[g * 4 + 2]), f2bf(OA[g * 4 + 3])};
      *(us4*)&orowA[mt * 32 + g * 8 + hi * 4] = oa;
      us4 ob = {f2bf(OB[g * 4 + 0]), f2bf(OB[g * 4 + 1]), f2bf(OB[g * 4 + 2]), f2bf(OB[g * 4 + 3])};
      *(us4*)&orowB[mt * 32 + g * 8 + hi * 4] = ob;
    }
  }
}

// ---------------- K4: depthwise 3x3 with 4-way split-combine + normalize ----------------
// Grid (bh, pblk): bh fastest -> XCD pinned per bh.
__global__ __launch_bounds__(256) void k_dwconv(const unsigned short* __restrict__ attnp,
                                                const float* __restrict__ lp,
                                                const float* __restrict__ w_dw,
                                                unsigned short* __restrict__ dwb) {
  int t = threadIdx.x;
  int d = t & 63;
  int pj = t >> 6;
  int p = blockIdx.y * 4 + pj;
  int bh = blockIdx.x;
  int b = bh >> 3, h = bh & 7;
  int yy = p / 48, xx = p % 48;
  const unsigned short* a0 = attnp + (size_t)bh * S_ * DH_ + d;
  const unsigned short* a1 = attnp + ((size_t)(16 + bh)) * S_ * DH_ + d;
  const unsigned short* a2 = attnp + ((size_t)(32 + bh)) * S_ * DH_ + d;
  const unsigned short* a3 = attnp + ((size_t)(48 + bh)) * S_ * DH_ + d;
  const float* l0 = lp + (size_t)bh * S_;
  const float* l1 = lp + (size_t)(16 + bh) * S_;
  const float* l2 = lp + (size_t)(32 + bh) * S_;
  const float* l3 = lp + (size_t)(48 + bh) * S_;
  int ch = h * 64 + d;
  float w[9];
#pragma unroll
  for (int i = 0; i < 9; i++) w[i] = w_dw[ch * 9 + i];
  float acc = 0.f;
#pragma unroll
  for (int dy = -1; dy <= 1; dy++) {
    int y2 = yy + dy;
    if (y2 < 0 || y2 >= 48) continue;
#pragma unroll
    for (int dx = -1; dx <= 1; dx++) {
      int x2 = xx + dx;
      if (x2 < 0 || x2 >= 48) continue;
      int p2 = y2 * 48 + x2;  // wave-uniform
      float rl = frcp(l0[p2] + l1[p2] + l2[p2] + l3[p2]);
      float v = (bf2f(a0[(size_t)p2 * DH_]) + bf2f(a1[(size_t)p2 * DH_]) +
                 bf2f(a2[(size_t)p2 * DH_]) + bf2f(a3[(size_t)p2 * DH_])) * rl;
      acc += v * w[(dy + 1) * 3 + dx + 1];
    }
  }
  dwb[((size_t)b * S_ + p) * INNER_ + ch] = f2bf(acc);
}

// ---------------- K6: channel LN + scales/shifts + final (pw bf16) ----------------
__global__ __launch_bounds__(256) void k_ln_final(const unsigned short* __restrict__ pw,
                                                  const float* __restrict__ gamma,
                                                  const float* __restrict__ beta,
                                                  const float* __restrict__ x,
                                                  float* __restrict__ out) {
  __shared__ float s_s0[32][8], s_s1[32][8], s_q0[32][8], s_q1[32][8];
  int t = threadIdx.x;
  int pl = t & 7, g = t >> 3;
  int b = blockIdx.y;
  int p = blockIdx.x * 16 + pl * 2;
  const unsigned short* pwb = pw + (size_t)b * INNER_ * S_ + p;
  float s0 = 0.f, s1 = 0.f, q0 = 0.f, q1 = 0.f;
#pragma unroll
  for (int j = 0; j < 16; j++) {
    unsigned u = *(const unsigned*)&pwb[(size_t)(g * 16 + j) * S_];
    float vx = bf2f((unsigned short)(u & 0xffffu));
    float vy = bf2f((unsigned short)(u >> 16));
    s0 += vx; s1 += vy;
    q0 += vx * vx; q1 += vy * vy;
  }
  s_s0[g][pl] = s0; s_s1[g][pl] = s1;
  s_q0[g][pl] = q0; s_q1[g][pl] = q1;
  __syncthreads();
  float t0 = 0.f, t1 = 0.f, u0 = 0.f, u1 = 0.f;
#pragma unroll
  for (int i = 0; i < 32; i++) {
    t0 += s_s0[i][pl]; t1 += s_s1[i][pl];
    u0 += s_q0[i][pl]; u1 += s_q1[i][pl];
  }
  float mu0 = t0 * (1.f / 512.f), mu1 = t1 * (1.f / 512.f);
  float rs0 = rsqrtf(u0 * (1.f / 512.f) - mu0 * mu0 + 1e-5f);
  float rs1 = rsqrtf(u1 * (1.f / 512.f) - mu1 * mu1 + 1e-5f);
  const float* xb = x + (size_t)b * C_ * S_ + p;
  float* ob = out + (size_t)b * C_ * S_ + p;
#pragma unroll
  for (int j = 0; j < 8; j++) {
    int cc = g * 8 + j;
    float ga = gamma[cc], be = beta[cc];
    float gs = gamma[cc + 256], bs = beta[cc + 256];
    unsigned pu = *(const unsigned*)&pwb[(size_t)cc * S_];
    unsigned su = *(const unsigned*)&pwb[(size_t)(cc + 256) * S_];
    float2 xv = *(const float2*)&xb[(size_t)cc * S_];
    float pv0 = bf2f((unsigned short)(pu & 0xffffu));
    float pv1 = bf2f((unsigned short)(pu >> 16));
    float sv0 = bf2f((unsigned short)(su & 0xffffu));
    float sv1 = bf2f((unsigned short)(su >> 16));
    float sc0 = (pv0 - mu0) * rs0 * ga + be;
    float sc1 = (pv1 - mu1) * rs1 * ga + be;
    float sh0 = (sv0 - mu0) * rs0 * gs + bs;
    float sh1 = (sv1 - mu1) * rs1 * gs + bs;
    float2 o;
    o.x = sh0 + xv.x * sc0;
    o.y = sh1 + xv.y * sc1;
    *(float2*)&ob[(size_t)cc * S_] = o;
  }
}

extern "C" void kernel_launch(void* const* d_in, const int* in_sizes, int n_in,
                              void* d_out, int out_size, void* d_ws, size_t ws_size,
                              hipStream_t stream) {
  const float* x = (const float*)d_in[0];
  const float* w_in = (const float*)d_in[1];
  const float* b_in = (const float*)d_in[2];
  const float* ss = (const float*)d_in[3];
  const float* w_dw = (const float*)d_in[4];
  const float* w_pw = (const float*)d_in[5];
  const float* gamma = (const float*)d_in[6];
  const float* beta = (const float*)d_in[7];
  float* out = (float*)d_out;
  char* ws = (char*)d_ws;

  unsigned short* xT = (unsigned short*)(ws + 0);           // 2,359,296
  unsigned short* w_inb = (unsigned short*)(ws + 2359296);  // 786,432
  unsigned short* w_pwb = (unsigned short*)(ws + 3145728);  // 524,288
  unsigned char* qn = (unsigned char*)(ws + 3670016);       // 2,359,296 fp8 [bh][p][64]
  unsigned char* kn = (unsigned char*)(ws + 6029312);       // 2,359,296 fp8 [bh][p][64]
  unsigned short* vT = (unsigned short*)(ws + 8388608);     // 4,718,592 bf16 [bh][d][p]
  unsigned short* dwb = (unsigned short*)(ws + 13107200);   // 4,718,592 bf16
  float* lp = (float*)(ws + 17825792);                      // 589,824  [4][16][2304] fp32
  unsigned short* attnp = (unsigned short*)(ws + 18415616); // bf16 [4][16][2304][64] = 18,874,368
  unsigned short* pw = (unsigned short*)(ws + 37289984);    // bf16 [2][512][2304] = 4,718,592

  k_prep<<<2848, 256, 0, stream>>>(x, w_in, w_pw, xT, w_inb, w_pwb);
  k_gemm_qkv<<<dim3(18, 24, 2), 256, 0, stream>>>(w_inb, xT, b_in, ss, qn, kn, vT);
  k_attn<<<dim3(16, 9, 4), 256, 0, stream>>>(qn, kn, vT, ss, attnp, lp);
  k_dwconv<<<dim3(16, 576), 256, 0, stream>>>(attnp, lp, w_dw, dwb);
  k_gemm2<<<dim3(36, 8, 2), 128, 0, stream>>>(w_pwb, dwb, pw, INNER_, S_, INNER_);
  k_ln_final<<<dim3(144, 2), 256, 0, stream>>>(pw, gamma, beta, x, out);
}

// Round 16
// 160.153 us; speedup vs baseline: 1.1111x; 1.1111x over previous
//
#include <hip/hip_runtime.h>

#define B_ 2
#define C_ 256
#define S_ 2304
#define DH_ 64
#define O3_ 1536
#define INNER_ 512
#define LOGSMAX 4.605170185988092f
#define LOG2E 1.4426950408889634f

typedef __attribute__((ext_vector_type(8))) short short8;
typedef __attribute__((ext_vector_type(4))) float f32x4;
typedef __attribute__((ext_vector_type(16))) float f32x16;
typedef __attribute__((ext_vector_type(4))) unsigned short us4;
typedef __attribute__((ext_vector_type(4))) unsigned u32x4;
typedef __bf16 bf16x8 __attribute__((ext_vector_type(8)));

__device__ __forceinline__ unsigned short f2bf(float f) {
  unsigned u = __builtin_bit_cast(unsigned, f);
  u += 0x7FFFu + ((u >> 16) & 1u);
  return (unsigned short)(u >> 16);
}
__device__ __forceinline__ float bf2f(unsigned short h) {
  return __builtin_bit_cast(float, (unsigned)h << 16);
}
__device__ __forceinline__ bf16x8 as_bf(short8 v) {
  return __builtin_bit_cast(bf16x8, v);
}
__device__ __forceinline__ float fexp2(float x) {
#if __has_builtin(__builtin_amdgcn_exp2f)
  return __builtin_amdgcn_exp2f(x);
#else
  return __expf(x * 0.6931471805599453f);
#endif
}
__device__ __forceinline__ float frcp(float x) {
#if __has_builtin(__builtin_amdgcn_rcpf)
  return __builtin_amdgcn_rcpf(x);
#else
  return 1.f / x;
#endif
}
// pack hi16 of two fp32 bit-patterns: (hi16(b)<<16)|hi16(a) — 1 v_perm_b32
__device__ __forceinline__ unsigned pack_hi16(unsigned b, unsigned a) {
  return __builtin_amdgcn_perm(b, a, 0x07060302u);
}
// half-up bf16 pair pack: dword low = bf16(a), high = bf16(b)
__device__ __forceinline__ unsigned pk2(float a, float b) {
  unsigned ua = __builtin_bit_cast(unsigned, a) + 0x8000u;
  unsigned ub = __builtin_bit_cast(unsigned, b) + 0x8000u;
  return pack_hi16(ub, ua);
}

// ---------------- K0: fused prep: x transpose + both weight converts ----------------
__global__ __launch_bounds__(256) void k_prep(const float* __restrict__ x,
                                              const float* __restrict__ w_in,
                                              const float* __restrict__ w_pw,
                                              unsigned short* __restrict__ xT,
                                              unsigned short* __restrict__ w_inb,
                                              unsigned short* __restrict__ w_pwb) {
  __shared__ float tile[64][65];
  int blk = blockIdx.x;
  int t = threadIdx.x;
  if (blk < 288) {  // transpose x [b][c][p] -> xT [b][p][c] bf16
    int p0 = (blk % 36) * 64, c0 = ((blk / 36) % 4) * 64, b = blk / 144;
    const float* xb = x + (size_t)b * C_ * S_;
#pragma unroll
    for (int i = 0; i < 16; i++) {
      int c = i * 4 + (t >> 6);
      int p = t & 63;
      tile[c][p] = xb[(size_t)(c0 + c) * S_ + p0 + p];
    }
    __syncthreads();
    unsigned short* xTb = xT + (size_t)b * S_ * C_;
#pragma unroll
    for (int i = 0; i < 16; i++) {
      int p = i * 4 + (t >> 6);
      int c = t & 63;
      xTb[(size_t)(p0 + p) * C_ + c0 + c] = f2bf(tile[c][p]);
    }
  } else if (blk < 288 + 1536) {
    int i = (blk - 288) * 256 + t;
    w_inb[i] = f2bf(w_in[i]);
  } else {
    int i = (blk - 1824) * 256 + t;
    w_pwb[i] = f2bf(w_pw[i]);
  }
}

// ---------------- K1: proj_in GEMM with fused bias + l2norm + scale epilogue ----------------
// 64x128 tile; M-tile 64 == one (head, q/k/v-seg) channel group.
// Writes qn/kn fp8 [bh][p][64] (scale*log2e folded into q), vT bf16 [bh][d][p] via LDS retile.
__global__ __launch_bounds__(256) void k_gemm_qkv(const unsigned short* __restrict__ A,
                                                  const unsigned short* __restrict__ BT,
                                                  const float* __restrict__ b_in,
                                                  const float* __restrict__ ss,
                                                  unsigned char* __restrict__ qn,
                                                  unsigned char* __restrict__ kn,
                                                  unsigned short* __restrict__ vT) {
  __shared__ __align__(16) unsigned short smem[64 * 72 + 128 * 72];
  unsigned short (*As)[72] = (unsigned short(*)[72])smem;
  unsigned short (*Bs)[72] = (unsigned short(*)[72])(smem + 64 * 72);
  int t = threadIdx.x;
  int lane = t & 63, wv = t >> 6;
  int quad = lane >> 4, r15 = lane & 15;
  int by = blockIdx.y;
  int m0 = by * 64, n0 = blockIdx.x * 128;
  int b = blockIdx.z;
  const unsigned short* BTb = BT + (size_t)b * S_ * C_;

  f32x4 acc[4][2] = {};

  int srA = t >> 2, scA = (t & 3) * 16;
  int srB = t >> 1, scB = (t & 1) * 32;
  const unsigned short* ag = A + (size_t)(m0 + srA) * C_ + scA;
  const unsigned short* bg = BTb + (size_t)(n0 + srB) * C_ + scB;

  for (int k0 = 0; k0 < C_; k0 += 64) {
    short8 a0 = *(const short8*)(ag + k0);
    short8 a1 = *(const short8*)(ag + k0 + 8);
    short8 b0 = *(const short8*)(bg + k0);
    short8 b1 = *(const short8*)(bg + k0 + 8);
    short8 b2 = *(const short8*)(bg + k0 + 16);
    short8 b3 = *(const short8*)(bg + k0 + 24);
    __syncthreads();
    *(short8*)&As[srA][scA] = a0;
    *(short8*)&As[srA][scA + 8] = a1;
    *(short8*)&Bs[srB][scB] = b0;
    *(short8*)&Bs[srB][scB + 8] = b1;
    *(short8*)&Bs[srB][scB + 16] = b2;
    *(short8*)&Bs[srB][scB + 24] = b3;
    __syncthreads();
#pragma unroll
    for (int ks = 0; ks < 2; ks++) {
      short8 af[4], bfr[2];
#pragma unroll
      for (int i = 0; i < 4; i++) af[i] = *(const short8*)&As[i * 16 + r15][ks * 32 + quad * 8];
#pragma unroll
      for (int j = 0; j < 2; j++) bfr[j] = *(const short8*)&Bs[wv * 32 + j * 16 + r15][ks * 32 + quad * 8];
#pragma unroll
      for (int i = 0; i < 4; i++)
#pragma unroll
        for (int j = 0; j < 2; j++)
          acc[i][j] = __builtin_amdgcn_mfma_f32_16x16x32_bf16(as_bf(af[i]), as_bf(bfr[j]), acc[i][j], 0, 0, 0);
    }
  }

  // epilogue: bias add, per-position l2norm (q/k) -> fp8; v -> vT bf16 [d][p] via LDS
  int h = by / 3, seg = by - h * 3;
  int bh = b * 8 + h;
  f32x4 bi[4];
#pragma unroll
  for (int i = 0; i < 4; i++) bi[i] = *(const f32x4*)&b_in[m0 + i * 16 + quad * 4];
  float bv[4][2][4];
  float ssq0 = 0.f, ssq1 = 0.f;
#pragma unroll
  for (int i = 0; i < 4; i++)
#pragma unroll
    for (int rr = 0; rr < 4; rr++) {
      float v0 = acc[i][0][rr] + bi[i][rr];
      float v1 = acc[i][1][rr] + bi[i][rr];
      bv[i][0][rr] = v0;
      bv[i][1][rr] = v1;
      ssq0 += v0 * v0;
      ssq1 += v1 * v1;
    }
  if (seg < 2) {
    float sc = (seg == 0) ? __expf(fminf(ss[h], LOGSMAX)) * LOG2E : 1.f;
    ssq0 += __shfl_xor(ssq0, 16);
    ssq0 += __shfl_xor(ssq0, 32);
    ssq1 += __shfl_xor(ssq1, 16);
    ssq1 += __shfl_xor(ssq1, 32);
    float inv0 = sc / fmaxf(sqrtf(ssq0), 1e-12f);
    float inv1 = sc / fmaxf(sqrtf(ssq1), 1e-12f);
    unsigned char* dst = (seg == 0 ? qn : kn) + (size_t)bh * S_ * DH_;
#pragma unroll
    for (int i = 0; i < 4; i++)
#pragma unroll
      for (int j = 0; j < 2; j++) {
        float iv = j ? inv1 : inv0;
        int pk = __builtin_amdgcn_cvt_pk_fp8_f32(bv[i][j][0] * iv, bv[i][j][1] * iv, 0, false);
        pk = __builtin_amdgcn_cvt_pk_fp8_f32(bv[i][j][2] * iv, bv[i][j][3] * iv, pk, true);
        int p = n0 + wv * 32 + j * 16 + r15;
        *(int*)&dst[(size_t)p * DH_ + i * 16 + quad * 4] = pk;
      }
  } else {
    // retile v through LDS: [d][p] tile (stride 132), then coalesced 16B stores
    __syncthreads();
    unsigned short* vt = smem;
#pragma unroll
    for (int i = 0; i < 4; i++)
#pragma unroll
      for (int j = 0; j < 2; j++) {
        int pcol = wv * 32 + j * 16 + r15;
#pragma unroll
        for (int rr = 0; rr < 4; rr++) {
          int d = i * 16 + quad * 4 + rr;
          vt[d * 132 + pcol] = f2bf(bv[i][j][rr]);
        }
      }
    __syncthreads();
    unsigned short* dst = vT + (size_t)bh * DH_ * S_;
    int dr = t >> 2, pc = (t & 3) * 32;
#pragma unroll
    for (int s2 = 0; s2 < 4; s2++) {
      short8 v8 = *(const short8*)&vt[dr * 132 + pc + s2 * 8];
      *(short8*)&dst[(size_t)dr * S_ + n0 + pc + s2 * 8] = v8;
    }
  }
}

// ---------------- K5: pw GEMM, 64x64 tile, 2 waves, bf16 output ----------------
__global__ __launch_bounds__(128) void k_gemm2(const unsigned short* __restrict__ A,
                                               const unsigned short* __restrict__ BT,
                                               unsigned short* __restrict__ outp,
                                               int M, int N, int K) {
  __shared__ __align__(16) unsigned short As[64][72];
  __shared__ __align__(16) unsigned short Bs[64][72];
  int t = threadIdx.x;
  int lane = t & 63, wv = t >> 6;
  int quad = lane >> 4, r15 = lane & 15;
  int m0 = blockIdx.y * 64, n0 = blockIdx.x * 64;
  int b = blockIdx.z;
  const unsigned short* BTb = BT + (size_t)b * N * K;

  f32x4 acc[4][2] = {};

  int sr = t >> 1, sc = (t & 1) * 32;
  const unsigned short* ag = A + (size_t)(m0 + sr) * K + sc;
  const unsigned short* bg = BTb + (size_t)(n0 + sr) * K + sc;

  for (int k0 = 0; k0 < K; k0 += 64) {
    short8 a0 = *(const short8*)(ag + k0);
    short8 a1 = *(const short8*)(ag + k0 + 8);
    short8 a2 = *(const short8*)(ag + k0 + 16);
    short8 a3 = *(const short8*)(ag + k0 + 24);
    short8 b0 = *(const short8*)(bg + k0);
    short8 b1 = *(const short8*)(bg + k0 + 8);
    short8 b2 = *(const short8*)(bg + k0 + 16);
    short8 b3 = *(const short8*)(bg + k0 + 24);
    __syncthreads();
    *(short8*)&As[sr][sc] = a0;
    *(short8*)&As[sr][sc + 8] = a1;
    *(short8*)&As[sr][sc + 16] = a2;
    *(short8*)&As[sr][sc + 24] = a3;
    *(short8*)&Bs[sr][sc] = b0;
    *(short8*)&Bs[sr][sc + 8] = b1;
    *(short8*)&Bs[sr][sc + 16] = b2;
    *(short8*)&Bs[sr][sc + 24] = b3;
    __syncthreads();
#pragma unroll
    for (int ks = 0; ks < 2; ks++) {
      short8 af[4], bfr[2];
#pragma unroll
      for (int i = 0; i < 4; i++) af[i] = *(const short8*)&As[i * 16 + r15][ks * 32 + quad * 8];
#pragma unroll
      for (int j = 0; j < 2; j++) bfr[j] = *(const short8*)&Bs[wv * 32 + j * 16 + r15][ks * 32 + quad * 8];
#pragma unroll
      for (int i = 0; i < 4; i++)
#pragma unroll
        for (int j = 0; j < 2; j++)
          acc[i][j] = __builtin_amdgcn_mfma_f32_16x16x32_bf16(as_bf(af[i]), as_bf(bfr[j]), acc[i][j], 0, 0, 0);
    }
  }
  unsigned short* Cb = outp + (size_t)b * M * N;
#pragma unroll
  for (int i = 0; i < 4; i++)
#pragma unroll
    for (int j = 0; j < 2; j++)
#pragma unroll
      for (int rr = 0; rr < 4; rr++) {
        int row = m0 + i * 16 + quad * 4 + rr;
        int col = n0 + wv * 32 + j * 16 + r15;
        Cb[(size_t)row * N + col] = f2bf(acc[i][j][rr]);
      }
}

// ---------------- K3: hybrid attention, direct vT staging, shfl P-relayout (R14 version) ----------------
// Q/K fp8 (S^T MFMA), P/V bf16 (O MFMA). 4 waves x 32q, split-K x4.
// Grid (bh, qtile, split): bh fastest -> XCD = bh%8 pinned.
__global__ __launch_bounds__(256) void k_attn(const unsigned char* __restrict__ qn,
                                              const unsigned char* __restrict__ kn,
                                              const unsigned short* __restrict__ vT,
                                              const float* __restrict__ ss,
                                              unsigned short* __restrict__ attnp,
                                              float* __restrict__ lp) {
  __shared__ __align__(16) unsigned char Ks[64][72];       // [key][d] fp8
  __shared__ __align__(16) unsigned short Vs[64][72];      // [d][key] bf16
  int t = threadIdx.x;
  int w = t >> 6;
  int lane = t & 63;
  int l31 = lane & 31, hi = lane >> 5;
  int bh = blockIdx.x;
  int q0 = blockIdx.y * 128 + w * 32;
  int split = blockIdx.z;
  int ktbase = split * 9;
  const unsigned char* qb = qn + (size_t)bh * S_ * DH_;
  const unsigned char* kb = kn + (size_t)bh * S_ * DH_;
  const unsigned short* vb = vT + (size_t)bh * DH_ * S_;
  float shift2 = __expf(fminf(ss[bh & 7], LOGSMAX)) * LOG2E;  // |s'| <= shift2

  // Q as fp8 B-fragment: n=query=l31, k(d) = ks*16 + hi*8 + j
  const unsigned char* qrow = qb + (size_t)(q0 + l31) * DH_ + hi * 8;
  long qf[4];
#pragma unroll
  for (int ks = 0; ks < 4; ks++) qf[ks] = *(const long*)(qrow + ks * 16);

  const f32x16 z16 = {};
  f32x16 O0 = z16, O1 = z16;
  float l_part = 0.f;

  // staging: K 64key x 64B fp8 (16B/thread), V 64d x 64key bf16 (32B/thread)
  int srow = t >> 2;
  int scolK = (t & 3) * 16;     // bytes
  int scolV = (t & 3) * 16;     // shorts
  const unsigned char* kg = kb + ((size_t)(ktbase * 64) + srow) * DH_ + scolK;
  const unsigned short* vg = vb + (size_t)srow * S_ + ktbase * 64 + scolV;

  uint4 kr = *(const uint4*)kg;
  short8 vr0 = *(const short8*)vg;
  short8 vr1 = *(const short8*)(vg + 8);

  for (int i = 0; i < 9; i++) {
    __syncthreads();
    *(uint4*)&Ks[srow][scolK] = kr;
    *(short8*)&Vs[srow][scolV] = vr0;
    *(short8*)&Vs[srow][scolV + 8] = vr1;
    __syncthreads();
    if (i < 8) {  // prefetch next tile
      kr = *(const uint4*)(kg + (size_t)(i + 1) * 64 * DH_);
      vr0 = *(const short8*)(vg + (i + 1) * 64);
      vr1 = *(const short8*)(vg + (i + 1) * 64 + 8);
    }
    // S^T = K Q^T : A = K fp8 frags (m=key), B = Q fp8 regs (n=query)
    f32x16 sc0, sc1;
    {
      long a0 = *(const long*)&Ks[l31][hi * 8];
      long a1 = *(const long*)&Ks[32 + l31][hi * 8];
      sc0 = __builtin_amdgcn_mfma_f32_32x32x16_fp8_fp8(a0, qf[0], z16, 0, 0, 0);
      sc1 = __builtin_amdgcn_mfma_f32_32x32x16_fp8_fp8(a1, qf[0], z16, 0, 0, 0);
    }
#pragma unroll
    for (int ks = 1; ks < 4; ks++) {
      long a0 = *(const long*)&Ks[l31][ks * 16 + hi * 8];
      long a1 = *(const long*)&Ks[32 + l31][ks * 16 + hi * 8];
      sc0 = __builtin_amdgcn_mfma_f32_32x32x16_fp8_fp8(a0, qf[ks], sc0, 0, 0, 0);
      sc1 = __builtin_amdgcn_mfma_f32_32x32x16_fp8_fp8(a1, qf[ks], sc1, 0, 0, 0);
    }
    // exp2 numerator; pack to bf16 dwords in C-layout; relayout to B-frag via shfl_xor(32).
#pragma unroll
    for (int mt = 0; mt < 2; mt++) {
      const f32x16& s = mt ? sc1 : sc0;
      unsigned pk[8];
      float lsum = 0.f;
#pragma unroll
      for (int g2 = 0; g2 < 4; g2++) {
        float e0 = fexp2(s[g2 * 4 + 0] - shift2);
        float e1 = fexp2(s[g2 * 4 + 1] - shift2);
        float e2 = fexp2(s[g2 * 4 + 2] - shift2);
        float e3 = fexp2(s[g2 * 4 + 3] - shift2);
        lsum += (e0 + e1) + (e2 + e3);
        pk[2 * g2] = pk2(e0, e1);
        pk[2 * g2 + 1] = pk2(e2, e3);
      }
      l_part += lsum;
#pragma unroll
      for (int half = 0; half < 2; half++) {
        int gb = half * 4;
        unsigned ya = hi ? pk[gb + 0] : pk[gb + 2];
        unsigned yb = hi ? pk[gb + 1] : pk[gb + 3];
        unsigned ra = __shfl_xor(ya, 32);
        unsigned rb = __shfl_xor(yb, 32);
        u32x4 fd;
        fd[0] = hi ? ra : pk[gb + 0];
        fd[1] = hi ? rb : pk[gb + 1];
        fd[2] = hi ? pk[gb + 2] : ra;
        fd[3] = hi ? pk[gb + 3] : rb;
        short8 pb = __builtin_bit_cast(short8, fd);
        int ks = mt * 2 + half;
        short8 va0 = *(const short8*)&Vs[l31][ks * 16 + hi * 8];
        short8 va1 = *(const short8*)&Vs[32 + l31][ks * 16 + hi * 8];
        O0 = __builtin_amdgcn_mfma_f32_32x32x16_bf16(as_bf(va0), as_bf(pb), O0, 0, 0, 0);
        O1 = __builtin_amdgcn_mfma_f32_32x32x16_bf16(as_bf(va1), as_bf(pb), O1, 0, 0, 0);
      }
    }
  }
  float l = l_part + __shfl_xor(l_part, 32);
  if (hi == 0) lp[((size_t)(split * 16 + bh)) * S_ + q0 + l31] = l;
  unsigned short* orow = attnp + (((size_t)(split * 16 + bh)) * S_ + q0 + l31) * DH_;
#pragma unroll
  for (int mt = 0; mt < 2; mt++) {
    const f32x16& O = mt ? O1 : O0;
#pragma unroll
    for (int g = 0; g < 4; g++) {
      us4 o4 = {f2bf(O[g * 4 + 0]), f2bf(O[g * 4 + 1]), f2bf(O[g * 4 + 2]), f2bf(O[g * 4 + 3])};
      *(us4*)&orow[mt * 32 + g * 8 + hi * 4] = o4;
    }
  }
}

// ---------------- K4: depthwise 3x3 with 4-way split-combine + normalize ----------------
// Grid (bh, pblk): bh fastest -> XCD pinned per bh.
__global__ __launch_bounds__(256) void k_dwconv(const unsigned short* __restrict__ attnp,
                                                const float* __restrict__ lp,
                                                const float* __restrict__ w_dw,
                                                unsigned short* __restrict__ dwb) {
  int t = threadIdx.x;
  int d = t & 63;
  int pj = t >> 6;
  int p = blockIdx.y * 4 + pj;
  int bh = blockIdx.x;
  int b = bh >> 3, h = bh & 7;
  int yy = p / 48, xx = p % 48;
  const unsigned short* a0 = attnp + (size_t)bh * S_ * DH_ + d;
  const unsigned short* a1 = attnp + ((size_t)(16 + bh)) * S_ * DH_ + d;
  const unsigned short* a2 = attnp + ((size_t)(32 + bh)) * S_ * DH_ + d;
  const unsigned short* a3 = attnp + ((size_t)(48 + bh)) * S_ * DH_ + d;
  const float* l0 = lp + (size_t)bh * S_;
  const float* l1 = lp + (size_t)(16 + bh) * S_;
  const float* l2 = lp + (size_t)(32 + bh) * S_;
  const float* l3 = lp + (size_t)(48 + bh) * S_;
  int ch = h * 64 + d;
  float w[9];
#pragma unroll
  for (int i = 0; i < 9; i++) w[i] = w_dw[ch * 9 + i];
  float acc = 0.f;
#pragma unroll
  for (int dy = -1; dy <= 1; dy++) {
    int y2 = yy + dy;
    if (y2 < 0 || y2 >= 48) continue;
#pragma unroll
    for (int dx = -1; dx <= 1; dx++) {
      int x2 = xx + dx;
      if (x2 < 0 || x2 >= 48) continue;
      int p2 = y2 * 48 + x2;  // wave-uniform
      float rl = frcp(l0[p2] + l1[p2] + l2[p2] + l3[p2]);
      float v = (bf2f(a0[(size_t)p2 * DH_]) + bf2f(a1[(size_t)p2 * DH_]) +
                 bf2f(a2[(size_t)p2 * DH_]) + bf2f(a3[(size_t)p2 * DH_])) * rl;
      acc += v * w[(dy + 1) * 3 + dx + 1];
    }
  }
  dwb[((size_t)b * S_ + p) * INNER_ + ch] = f2bf(acc);
}

// ---------------- K6: channel LN + scales/shifts + final (pw bf16) ----------------
__global__ __launch_bounds__(256) void k_ln_final(const unsigned short* __restrict__ pw,
                                                  const float* __restrict__ gamma,
                                                  const float* __restrict__ beta,
                                                  const float* __restrict__ x,
                                                  float* __restrict__ out) {
  __shared__ float s_s0[32][8], s_s1[32][8], s_q0[32][8], s_q1[32][8];
  int t = threadIdx.x;
  int pl = t & 7, g = t >> 3;
  int b = blockIdx.y;
  int p = blockIdx.x * 16 + pl * 2;
  const unsigned short* pwb = pw + (size_t)b * INNER_ * S_ + p;
  float s0 = 0.f, s1 = 0.f, q0 = 0.f, q1 = 0.f;
#pragma unroll
  for (int j = 0; j < 16; j++) {
    unsigned u = *(const unsigned*)&pwb[(size_t)(g * 16 + j) * S_];
    float vx = bf2f((unsigned short)(u & 0xffffu));
    float vy = bf2f((unsigned short)(u >> 16));
    s0 += vx; s1 += vy;
    q0 += vx * vx; q1 += vy * vy;
  }
  s_s0[g][pl] = s0; s_s1[g][pl] = s1;
  s_q0[g][pl] = q0; s_q1[g][pl] = q1;
  __syncthreads();
  float t0 = 0.f, t1 = 0.f, u0 = 0.f, u1 = 0.f;
#pragma unroll
  for (int i = 0; i < 32; i++) {
    t0 += s_s0[i][pl]; t1 += s_s1[i][pl];
    u0 += s_q0[i][pl]; u1 += s_q1[i][pl];
  }
  float mu0 = t0 * (1.f / 512.f), mu1 = t1 * (1.f / 512.f);
  float rs0 = rsqrtf(u0 * (1.f / 512.f) - mu0 * mu0 + 1e-5f);
  float rs1 = rsqrtf(u1 * (1.f / 512.f) - mu1 * mu1 + 1e-5f);
  const float* xb = x + (size_t)b * C_ * S_ + p;
  float* ob = out + (size_t)b * C_ * S_ + p;
#pragma unroll
  for (int j = 0; j < 8; j++) {
    int cc = g * 8 + j;
    float ga = gamma[cc], be = beta[cc];
    float gs = gamma[cc + 256], bs = beta[cc + 256];
    unsigned pu = *(const unsigned*)&pwb[(size_t)cc * S_];
    unsigned su = *(const unsigned*)&pwb[(size_t)(cc + 256) * S_];
    float2 xv = *(const float2*)&xb[(size_t)cc * S_];
    float pv0 = bf2f((unsigned short)(pu & 0xffffu));
    float pv1 = bf2f((unsigned short)(pu >> 16));
    float sv0 = bf2f((unsigned short)(su & 0xffffu));
    float sv1 = bf2f((unsigned short)(su >> 16));
    float sc0 = (pv0 - mu0) * rs0 * ga + be;
    float sc1 = (pv1 - mu1) * rs1 * ga + be;
    float sh0 = (sv0 - mu0) * rs0 * gs + bs;
    float sh1 = (sv1 - mu1) * rs1 * gs + bs;
    float2 o;
    o.x = sh0 + xv.x * sc0;
    o.y = sh1 + xv.y * sc1;
    *(float2*)&ob[(size_t)cc * S_] = o;
  }
}

extern "C" void kernel_launch(void* const* d_in, const int* in_sizes, int n_in,
                              void* d_out, int out_size, void* d_ws, size_t ws_size,
                              hipStream_t stream) {
  const float* x = (const float*)d_in[0];
  const float* w_in = (const float*)d_in[1];
  const float* b_in = (const float*)d_in[2];
  const float* ss = (const float*)d_in[3];
  const float* w_dw = (const float*)d_in[4];
  const float* w_pw = (const float*)d_in[5];
  const float* gamma = (const float*)d_in[6];
  const float* beta = (const float*)d_in[7];
  float* out = (float*)d_out;
  char* ws = (char*)d_ws;

  unsigned short* xT = (unsigned short*)(ws + 0);           // 2,359,296
  unsigned short* w_inb = (unsigned short*)(ws + 2359296);  // 786,432
  unsigned short* w_pwb = (unsigned short*)(ws + 3145728);  // 524,288
  unsigned char* qn = (unsigned char*)(ws + 3670016);       // 2,359,296 fp8 [bh][p][64]
  unsigned char* kn = (unsigned char*)(ws + 6029312);       // 2,359,296 fp8 [bh][p][64]
  unsigned short* vT = (unsigned short*)(ws + 8388608);     // 4,718,592 bf16 [bh][d][p]
  unsigned short* dwb = (unsigned short*)(ws + 13107200);   // 4,718,592 bf16
  float* lp = (float*)(ws + 17825792);                      // 589,824  [4][16][2304] fp32
  unsigned short* attnp = (unsigned short*)(ws + 18415616); // bf16 [4][16][2304][64] = 18,874,368
  unsigned short* pw = (unsigned short*)(ws + 37289984);    // bf16 [2][512][2304] = 4,718,592

  k_prep<<<2848, 256, 0, stream>>>(x, w_in, w_pw, xT, w_inb, w_pwb);
  k_gemm_qkv<<<dim3(18, 24, 2), 256, 0, stream>>>(w_inb, xT, b_in, ss, qn, kn, vT);
  k_attn<<<dim3(16, 18, 4), 256, 0, stream>>>(qn, kn, vT, ss, attnp, lp);
  k_dwconv<<<dim3(16, 576), 256, 0, stream>>>(attnp, lp, w_dw, dwb);
  k_gemm2<<<dim3(36, 8, 2), 128, 0, stream>>>(w_pwb, dwb, pw, INNER_, S_, INNER_);
  k_ln_final<<<dim3(144, 2), 256, 0, stream>>>(pw, gamma, beta, x, out);
}

// Round 17
// 153.042 us; speedup vs baseline: 1.1627x; 1.0465x over previous
//
#include <hip/hip_runtime.h>

#define B_ 2
#define C_ 256
#define S_ 2304
#define DH_ 64
#define O3_ 1536
#define INNER_ 512
#define LOGSMAX 4.605170185988092f
#define LOG2E 1.4426950408889634f

typedef __attribute__((ext_vector_type(8))) short short8;
typedef __attribute__((ext_vector_type(4))) float f32x4;
typedef __attribute__((ext_vector_type(16))) float f32x16;
typedef __attribute__((ext_vector_type(4))) unsigned short us4;
typedef __attribute__((ext_vector_type(4))) unsigned u32x4;
typedef __bf16 bf16x8 __attribute__((ext_vector_type(8)));

__device__ __forceinline__ unsigned short f2bf(float f) {
  unsigned u = __builtin_bit_cast(unsigned, f);
  u += 0x7FFFu + ((u >> 16) & 1u);
  return (unsigned short)(u >> 16);
}
__device__ __forceinline__ float bf2f(unsigned short h) {
  return __builtin_bit_cast(float, (unsigned)h << 16);
}
__device__ __forceinline__ bf16x8 as_bf(short8 v) {
  return __builtin_bit_cast(bf16x8, v);
}
__device__ __forceinline__ float fexp2(float x) {
#if __has_builtin(__builtin_amdgcn_exp2f)
  return __builtin_amdgcn_exp2f(x);
#else
  return __expf(x * 0.6931471805599453f);
#endif
}
__device__ __forceinline__ float frcp(float x) {
#if __has_builtin(__builtin_amdgcn_rcpf)
  return __builtin_amdgcn_rcpf(x);
#else
  return 1.f / x;
#endif
}
// pack hi16 of two fp32 bit-patterns: (hi16(b)<<16)|hi16(a) — 1 v_perm_b32
__device__ __forceinline__ unsigned pack_hi16(unsigned b, unsigned a) {
  return __builtin_amdgcn_perm(b, a, 0x07060302u);
}
// half-up bf16 pair pack: dword low = bf16(a), high = bf16(b)
__device__ __forceinline__ unsigned pk2(float a, float b) {
  unsigned ua = __builtin_bit_cast(unsigned, a) + 0x8000u;
  unsigned ub = __builtin_bit_cast(unsigned, b) + 0x8000u;
  return pack_hi16(ub, ua);
}

// ---------------- K0: fused prep: x transpose + both weight converts ----------------
__global__ __launch_bounds__(256) void k_prep(const float* __restrict__ x,
                                              const float* __restrict__ w_in,
                                              const float* __restrict__ w_pw,
                                              unsigned short* __restrict__ xT,
                                              unsigned short* __restrict__ w_inb,
                                              unsigned short* __restrict__ w_pwb) {
  __shared__ float tile[64][65];
  int blk = blockIdx.x;
  int t = threadIdx.x;
  if (blk < 288) {  // transpose x [b][c][p] -> xT [b][p][c] bf16
    int p0 = (blk % 36) * 64, c0 = ((blk / 36) % 4) * 64, b = blk / 144;
    const float* xb = x + (size_t)b * C_ * S_;
#pragma unroll
    for (int i = 0; i < 16; i++) {
      int c = i * 4 + (t >> 6);
      int p = t & 63;
      tile[c][p] = xb[(size_t)(c0 + c) * S_ + p0 + p];
    }
    __syncthreads();
    unsigned short* xTb = xT + (size_t)b * S_ * C_;
#pragma unroll
    for (int i = 0; i < 16; i++) {
      int p = i * 4 + (t >> 6);
      int c = t & 63;
      xTb[(size_t)(p0 + p) * C_ + c0 + c] = f2bf(tile[c][p]);
    }
  } else if (blk < 288 + 1536) {
    int i = (blk - 288) * 256 + t;
    w_inb[i] = f2bf(w_in[i]);
  } else {
    int i = (blk - 1824) * 256 + t;
    w_pwb[i] = f2bf(w_pw[i]);
  }
}

// ---------------- K1: proj_in GEMM with fused bias + l2norm + scale epilogue ----------------
// 64x128 tile; M-tile 64 == one (head, q/k/v-seg) channel group.
// Writes qn/kn fp8 [bh][p][64] (scale*log2e folded into q), vT bf16 [bh][d][p] via LDS retile.
__global__ __launch_bounds__(256) void k_gemm_qkv(const unsigned short* __restrict__ A,
                                                  const unsigned short* __restrict__ BT,
                                                  const float* __restrict__ b_in,
                                                  const float* __restrict__ ss,
                                                  unsigned char* __restrict__ qn,
                                                  unsigned char* __restrict__ kn,
                                                  unsigned short* __restrict__ vT) {
  __shared__ __align__(16) unsigned short smem[64 * 72 + 128 * 72];
  unsigned short (*As)[72] = (unsigned short(*)[72])smem;
  unsigned short (*Bs)[72] = (unsigned short(*)[72])(smem + 64 * 72);
  int t = threadIdx.x;
  int lane = t & 63, wv = t >> 6;
  int quad = lane >> 4, r15 = lane & 15;
  int by = blockIdx.y;
  int m0 = by * 64, n0 = blockIdx.x * 128;
  int b = blockIdx.z;
  const unsigned short* BTb = BT + (size_t)b * S_ * C_;

  f32x4 acc[4][2] = {};

  int srA = t >> 2, scA = (t & 3) * 16;
  int srB = t >> 1, scB = (t & 1) * 32;
  const unsigned short* ag = A + (size_t)(m0 + srA) * C_ + scA;
  const unsigned short* bg = BTb + (size_t)(n0 + srB) * C_ + scB;

  for (int k0 = 0; k0 < C_; k0 += 64) {
    short8 a0 = *(const short8*)(ag + k0);
    short8 a1 = *(const short8*)(ag + k0 + 8);
    short8 b0 = *(const short8*)(bg + k0);
    short8 b1 = *(const short8*)(bg + k0 + 8);
    short8 b2 = *(const short8*)(bg + k0 + 16);
    short8 b3 = *(const short8*)(bg + k0 + 24);
    __syncthreads();
    *(short8*)&As[srA][scA] = a0;
    *(short8*)&As[srA][scA + 8] = a1;
    *(short8*)&Bs[srB][scB] = b0;
    *(short8*)&Bs[srB][scB + 8] = b1;
    *(short8*)&Bs[srB][scB + 16] = b2;
    *(short8*)&Bs[srB][scB + 24] = b3;
    __syncthreads();
#pragma unroll
    for (int ks = 0; ks < 2; ks++) {
      short8 af[4], bfr[2];
#pragma unroll
      for (int i = 0; i < 4; i++) af[i] = *(const short8*)&As[i * 16 + r15][ks * 32 + quad * 8];
#pragma unroll
      for (int j = 0; j < 2; j++) bfr[j] = *(const short8*)&Bs[wv * 32 + j * 16 + r15][ks * 32 + quad * 8];
#pragma unroll
      for (int i = 0; i < 4; i++)
#pragma unroll
        for (int j = 0; j < 2; j++)
          acc[i][j] = __builtin_amdgcn_mfma_f32_16x16x32_bf16(as_bf(af[i]), as_bf(bfr[j]), acc[i][j], 0, 0, 0);
    }
  }

  // epilogue: bias add, per-position l2norm (q/k) -> fp8; v -> vT bf16 [d][p] via LDS
  int h = by / 3, seg = by - h * 3;
  int bh = b * 8 + h;
  f32x4 bi[4];
#pragma unroll
  for (int i = 0; i < 4; i++) bi[i] = *(const f32x4*)&b_in[m0 + i * 16 + quad * 4];
  float bv[4][2][4];
  float ssq0 = 0.f, ssq1 = 0.f;
#pragma unroll
  for (int i = 0; i < 4; i++)
#pragma unroll
    for (int rr = 0; rr < 4; rr++) {
      float v0 = acc[i][0][rr] + bi[i][rr];
      float v1 = acc[i][1][rr] + bi[i][rr];
      bv[i][0][rr] = v0;
      bv[i][1][rr] = v1;
      ssq0 += v0 * v0;
      ssq1 += v1 * v1;
    }
  if (seg < 2) {
    float sc = (seg == 0) ? __expf(fminf(ss[h], LOGSMAX)) * LOG2E : 1.f;
    ssq0 += __shfl_xor(ssq0, 16);
    ssq0 += __shfl_xor(ssq0, 32);
    ssq1 += __shfl_xor(ssq1, 16);
    ssq1 += __shfl_xor(ssq1, 32);
    float inv0 = sc / fmaxf(sqrtf(ssq0), 1e-12f);
    float inv1 = sc / fmaxf(sqrtf(ssq1), 1e-12f);
    unsigned char* dst = (seg == 0 ? qn : kn) + (size_t)bh * S_ * DH_;
#pragma unroll
    for (int i = 0; i < 4; i++)
#pragma unroll
      for (int j = 0; j < 2; j++) {
        float iv = j ? inv1 : inv0;
        int pk = __builtin_amdgcn_cvt_pk_fp8_f32(bv[i][j][0] * iv, bv[i][j][1] * iv, 0, false);
        pk = __builtin_amdgcn_cvt_pk_fp8_f32(bv[i][j][2] * iv, bv[i][j][3] * iv, pk, true);
        int p = n0 + wv * 32 + j * 16 + r15;
        *(int*)&dst[(size_t)p * DH_ + i * 16 + quad * 4] = pk;
      }
  } else {
    // retile v through LDS: [d][p] tile (stride 132), then coalesced 16B stores
    __syncthreads();
    unsigned short* vt = smem;
#pragma unroll
    for (int i = 0; i < 4; i++)
#pragma unroll
      for (int j = 0; j < 2; j++) {
        int pcol = wv * 32 + j * 16 + r15;
#pragma unroll
        for (int rr = 0; rr < 4; rr++) {
          int d = i * 16 + quad * 4 + rr;
          vt[d * 132 + pcol] = f2bf(bv[i][j][rr]);
        }
      }
    __syncthreads();
    unsigned short* dst = vT + (size_t)bh * DH_ * S_;
    int dr = t >> 2, pc = (t & 3) * 32;
#pragma unroll
    for (int s2 = 0; s2 < 4; s2++) {
      short8 v8 = *(const short8*)&vt[dr * 132 + pc + s2 * 8];
      *(short8*)&dst[(size_t)dr * S_ + n0 + pc + s2 * 8] = v8;
    }
  }
}

// ---------------- K5: pw GEMM, 64x64 tile, 2 waves, bf16 output ----------------
__global__ __launch_bounds__(128) void k_gemm2(const unsigned short* __restrict__ A,
                                               const unsigned short* __restrict__ BT,
                                               unsigned short* __restrict__ outp,
                                               int M, int N, int K) {
  __shared__ __align__(16) unsigned short As[64][72];
  __shared__ __align__(16) unsigned short Bs[64][72];
  int t = threadIdx.x;
  int lane = t & 63, wv = t >> 6;
  int quad = lane >> 4, r15 = lane & 15;
  int m0 = blockIdx.y * 64, n0 = blockIdx.x * 64;
  int b = blockIdx.z;
  const unsigned short* BTb = BT + (size_t)b * N * K;

  f32x4 acc[4][2] = {};

  int sr = t >> 1, sc = (t & 1) * 32;
  const unsigned short* ag = A + (size_t)(m0 + sr) * K + sc;
  const unsigned short* bg = BTb + (size_t)(n0 + sr) * K + sc;

  for (int k0 = 0; k0 < K; k0 += 64) {
    short8 a0 = *(const short8*)(ag + k0);
    short8 a1 = *(const short8*)(ag + k0 + 8);
    short8 a2 = *(const short8*)(ag + k0 + 16);
    short8 a3 = *(const short8*)(ag + k0 + 24);
    short8 b0 = *(const short8*)(bg + k0);
    short8 b1 = *(const short8*)(bg + k0 + 8);
    short8 b2 = *(const short8*)(bg + k0 + 16);
    short8 b3 = *(const short8*)(bg + k0 + 24);
    __syncthreads();
    *(short8*)&As[sr][sc] = a0;
    *(short8*)&As[sr][sc + 8] = a1;
    *(short8*)&As[sr][sc + 16] = a2;
    *(short8*)&As[sr][sc + 24] = a3;
    *(short8*)&Bs[sr][sc] = b0;
    *(short8*)&Bs[sr][sc + 8] = b1;
    *(short8*)&Bs[sr][sc + 16] = b2;
    *(short8*)&Bs[sr][sc + 24] = b3;
    __syncthreads();
#pragma unroll
    for (int ks = 0; ks < 2; ks++) {
      short8 af[4], bfr[2];
#pragma unroll
      for (int i = 0; i < 4; i++) af[i] = *(const short8*)&As[i * 16 + r15][ks * 32 + quad * 8];
#pragma unroll
      for (int j = 0; j < 2; j++) bfr[j] = *(const short8*)&Bs[wv * 32 + j * 16 + r15][ks * 32 + quad * 8];
#pragma unroll
      for (int i = 0; i < 4; i++)
#pragma unroll
        for (int j = 0; j < 2; j++)
          acc[i][j] = __builtin_amdgcn_mfma_f32_16x16x32_bf16(as_bf(af[i]), as_bf(bfr[j]), acc[i][j], 0, 0, 0);
    }
  }
  unsigned short* Cb = outp + (size_t)b * M * N;
#pragma unroll
  for (int i = 0; i < 4; i++)
#pragma unroll
    for (int j = 0; j < 2; j++)
#pragma unroll
      for (int rr = 0; rr < 4; rr++) {
        int row = m0 + i * 16 + quad * 4 + rr;
        int col = n0 + wv * 32 + j * 16 + r15;
        Cb[(size_t)row * N + col] = f2bf(acc[i][j][rr]);
      }
}

// ---------------- K3: hybrid attention, shiftless softmax (shift cancels in O/l) ----------------
// Q/K fp8 (S^T MFMA), P/V bf16 (O MFMA). 4 waves x 32q, split-K x4.
// Grid (bh, qtile, split): bh fastest -> XCD = bh%8 pinned.
__global__ __launch_bounds__(256) void k_attn(const unsigned char* __restrict__ qn,
                                              const unsigned char* __restrict__ kn,
                                              const unsigned short* __restrict__ vT,
                                              unsigned short* __restrict__ attnp,
                                              float* __restrict__ lp) {
  __shared__ __align__(16) unsigned char Ks[64][72];       // [key][d] fp8
  __shared__ __align__(16) unsigned short Vs[64][72];      // [d][key] bf16
  int t = threadIdx.x;
  int w = t >> 6;
  int lane = t & 63;
  int l31 = lane & 31, hi = lane >> 5;
  int bh = blockIdx.x;
  int q0 = blockIdx.y * 128 + w * 32;
  int split = blockIdx.z;
  int ktbase = split * 9;
  const unsigned char* qb = qn + (size_t)bh * S_ * DH_;
  const unsigned char* kb = kn + (size_t)bh * S_ * DH_;
  const unsigned short* vb = vT + (size_t)bh * DH_ * S_;

  // Q as fp8 B-fragment: n=query=l31, k(d) = ks*16 + hi*8 + j
  const unsigned char* qrow = qb + (size_t)(q0 + l31) * DH_ + hi * 8;
  long qf[4];
#pragma unroll
  for (int ks = 0; ks < 4; ks++) qf[ks] = *(const long*)(qrow + ks * 16);

  const f32x16 z16 = {};
  f32x16 O0 = z16, O1 = z16;
  float l_part = 0.f;

  // staging: K 64key x 64B fp8 (16B/thread), V 64d x 64key bf16 (32B/thread)
  int srow = t >> 2;
  int scolK = (t & 3) * 16;     // bytes
  int scolV = (t & 3) * 16;     // shorts
  const unsigned char* kg = kb + ((size_t)(ktbase * 64) + srow) * DH_ + scolK;
  const unsigned short* vg = vb + (size_t)srow * S_ + ktbase * 64 + scolV;

  uint4 kr = *(const uint4*)kg;
  short8 vr0 = *(const short8*)vg;
  short8 vr1 = *(const short8*)(vg + 8);

  for (int i = 0; i < 9; i++) {
    __syncthreads();
    *(uint4*)&Ks[srow][scolK] = kr;
    *(short8*)&Vs[srow][scolV] = vr0;
    *(short8*)&Vs[srow][scolV + 8] = vr1;
    __syncthreads();
    if (i < 8) {  // prefetch next tile
      kr = *(const uint4*)(kg + (size_t)(i + 1) * 64 * DH_);
      vr0 = *(const short8*)(vg + (i + 1) * 64);
      vr1 = *(const short8*)(vg + (i + 1) * 64 + 8);
    }
    // S^T = K Q^T : A = K fp8 frags (m=key), B = Q fp8 regs (n=query)
    f32x16 sc0, sc1;
    {
      long a0 = *(const long*)&Ks[l31][hi * 8];
      long a1 = *(const long*)&Ks[32 + l31][hi * 8];
      sc0 = __builtin_amdgcn_mfma_f32_32x32x16_fp8_fp8(a0, qf[0], z16, 0, 0, 0);
      sc1 = __builtin_amdgcn_mfma_f32_32x32x16_fp8_fp8(a1, qf[0], z16, 0, 0, 0);
    }
#pragma unroll
    for (int ks = 1; ks < 4; ks++) {
      long a0 = *(const long*)&Ks[l31][ks * 16 + hi * 8];
      long a1 = *(const long*)&Ks[32 + l31][ks * 16 + hi * 8];
      sc0 = __builtin_amdgcn_mfma_f32_32x32x16_fp8_fp8(a0, qf[ks], sc0, 0, 0, 0);
      sc1 = __builtin_amdgcn_mfma_f32_32x32x16_fp8_fp8(a1, qf[ks], sc1, 0, 0, 0);
    }
    // shiftless exp2 numerator (|s| <= 0.26: safe; constant shift cancels in O/l);
    // pack to bf16 dwords in C-layout; relayout to B-frag via shfl_xor(32).
#pragma unroll
    for (int mt = 0; mt < 2; mt++) {
      const f32x16& s = mt ? sc1 : sc0;
      unsigned pk[8];
      float lsum = 0.f;
#pragma unroll
      for (int g2 = 0; g2 < 4; g2++) {
        float e0 = fexp2(s[g2 * 4 + 0]);
        float e1 = fexp2(s[g2 * 4 + 1]);
        float e2 = fexp2(s[g2 * 4 + 2]);
        float e3 = fexp2(s[g2 * 4 + 3]);
        lsum += (e0 + e1) + (e2 + e3);
        pk[2 * g2] = pk2(e0, e1);
        pk[2 * g2 + 1] = pk2(e2, e3);
      }
      l_part += lsum;
#pragma unroll
      for (int half = 0; half < 2; half++) {
        int gb = half * 4;
        unsigned ya = hi ? pk[gb + 0] : pk[gb + 2];
        unsigned yb = hi ? pk[gb + 1] : pk[gb + 3];
        unsigned ra = __shfl_xor(ya, 32);
        unsigned rb = __shfl_xor(yb, 32);
        u32x4 fd;
        fd[0] = hi ? ra : pk[gb + 0];
        fd[1] = hi ? rb : pk[gb + 1];
        fd[2] = hi ? pk[gb + 2] : ra;
        fd[3] = hi ? pk[gb + 3] : rb;
        short8 pb = __builtin_bit_cast(short8, fd);
        int ks = mt * 2 + half;
        short8 va0 = *(const short8*)&Vs[l31][ks * 16 + hi * 8];
        short8 va1 = *(const short8*)&Vs[32 + l31][ks * 16 + hi * 8];
        O0 = __builtin_amdgcn_mfma_f32_32x32x16_bf16(as_bf(va0), as_bf(pb), O0, 0, 0, 0);
        O1 = __builtin_amdgcn_mfma_f32_32x32x16_bf16(as_bf(va1), as_bf(pb), O1, 0, 0, 0);
      }
    }
  }
  float l = l_part + __shfl_xor(l_part, 32);
  if (hi == 0) lp[((size_t)(split * 16 + bh)) * S_ + q0 + l31] = l;
  unsigned short* orow = attnp + (((size_t)(split * 16 + bh)) * S_ + q0 + l31) * DH_;
#pragma unroll
  for (int mt = 0; mt < 2; mt++) {
    const f32x16& O = mt ? O1 : O0;
#pragma unroll
    for (int g = 0; g < 4; g++) {
      us4 o4 = {f2bf(O[g * 4 + 0]), f2bf(O[g * 4 + 1]), f2bf(O[g * 4 + 2]), f2bf(O[g * 4 + 3])};
      *(us4*)&orow[mt * 32 + g * 8 + hi * 4] = o4;
    }
  }
}

// ---------------- K4: depthwise 3x3, LDS-shared 3x6 combined stencil tile ----------------
// Block = 4 consecutive positions (same row; 48%4==0). Combine+normalize each stencil
// position ONCE into LDS, then 9 conflict-free ds_read_b32 taps per thread.
// Grid (bh, pblk): bh fastest -> XCD pinned per bh.
__global__ __launch_bounds__(256) void k_dwconv(const unsigned short* __restrict__ attnp,
                                                const float* __restrict__ lp,
                                                const float* __restrict__ w_dw,
                                                unsigned short* __restrict__ dwb) {
  __shared__ float sc[3][6][64];
  int t = threadIdx.x;
  int d = t & 63;
  int wv = t >> 6;
  int bh = blockIdx.x;
  int b = bh >> 3, h = bh & 7;
  int p0 = blockIdx.y * 4;
  int x0 = p0 % 48, y0 = p0 / 48;
  const unsigned short* a0 = attnp + (size_t)bh * S_ * DH_ + d;
  const unsigned short* a1 = attnp + ((size_t)(16 + bh)) * S_ * DH_ + d;
  const unsigned short* a2 = attnp + ((size_t)(32 + bh)) * S_ * DH_ + d;
  const unsigned short* a3 = attnp + ((size_t)(48 + bh)) * S_ * DH_ + d;
  const float* l0 = lp + (size_t)bh * S_;
  const float* l1 = lp + (size_t)(16 + bh) * S_;
  const float* l2 = lp + (size_t)(32 + bh) * S_;
  const float* l3 = lp + (size_t)(48 + bh) * S_;
  // build 3x6 combined tile: pos i = ry*6 + cx; 4 waves cover 18 positions
  for (int i = wv; i < 18; i += 4) {
    int ry = i / 6, cx = i - ry * 6;
    int y2 = y0 + ry - 1, x2 = x0 + cx - 1;
    float val = 0.f;
    if (y2 >= 0 && y2 < 48 && x2 >= 0 && x2 < 48) {
      int p2 = y2 * 48 + x2;  // wave-uniform
      float rl = frcp(l0[p2] + l1[p2] + l2[p2] + l3[p2]);
      val = (bf2f(a0[(size_t)p2 * DH_]) + bf2f(a1[(size_t)p2 * DH_]) +
             bf2f(a2[(size_t)p2 * DH_]) + bf2f(a3[(size_t)p2 * DH_])) * rl;
    }
    sc[ry][cx][d] = val;
  }
  __syncthreads();
  int ch = h * 64 + d;
  float w[9];
#pragma unroll
  for (int i = 0; i < 9; i++) w[i] = w_dw[ch * 9 + i];
  float acc = 0.f;
#pragma unroll
  for (int dy = 0; dy < 3; dy++)
#pragma unroll
    for (int dx = 0; dx < 3; dx++)
      acc += sc[dy][wv + dx][d] * w[dy * 3 + dx];
  dwb[((size_t)b * S_ + p0 + wv) * INNER_ + ch] = f2bf(acc);
}

// ---------------- K6: channel LN + scales/shifts + final (pw bf16) ----------------
__global__ __launch_bounds__(256) void k_ln_final(const unsigned short* __restrict__ pw,
                                                  const float* __restrict__ gamma,
                                                  const float* __restrict__ beta,
                                                  const float* __restrict__ x,
                                                  float* __restrict__ out) {
  __shared__ float s_s0[32][8], s_s1[32][8], s_q0[32][8], s_q1[32][8];
  int t = threadIdx.x;
  int pl = t & 7, g = t >> 3;
  int b = blockIdx.y;
  int p = blockIdx.x * 16 + pl * 2;
  const unsigned short* pwb = pw + (size_t)b * INNER_ * S_ + p;
  float s0 = 0.f, s1 = 0.f, q0 = 0.f, q1 = 0.f;
#pragma unroll
  for (int j = 0; j < 16; j++) {
    unsigned u = *(const unsigned*)&pwb[(size_t)(g * 16 + j) * S_];
    float vx = bf2f((unsigned short)(u & 0xffffu));
    float vy = bf2f((unsigned short)(u >> 16));
    s0 += vx; s1 += vy;
    q0 += vx * vx; q1 += vy * vy;
  }
  s_s0[g][pl] = s0; s_s1[g][pl] = s1;
  s_q0[g][pl] = q0; s_q1[g][pl] = q1;
  __syncthreads();
  float t0 = 0.f, t1 = 0.f, u0 = 0.f, u1 = 0.f;
#pragma unroll
  for (int i = 0; i < 32; i++) {
    t0 += s_s0[i][pl]; t1 += s_s1[i][pl];
    u0 += s_q0[i][pl]; u1 += s_q1[i][pl];
  }
  float mu0 = t0 * (1.f / 512.f), mu1 = t1 * (1.f / 512.f);
  float rs0 = rsqrtf(u0 * (1.f / 512.f) - mu0 * mu0 + 1e-5f);
  float rs1 = rsqrtf(u1 * (1.f / 512.f) - mu1 * mu1 + 1e-5f);
  const float* xb = x + (size_t)b * C_ * S_ + p;
  float* ob = out + (size_t)b * C_ * S_ + p;
#pragma unroll
  for (int j = 0; j < 8; j++) {
    int cc = g * 8 + j;
    float ga = gamma[cc], be = beta[cc];
    float gs = gamma[cc + 256], bs = beta[cc + 256];
    unsigned pu = *(const unsigned*)&pwb[(size_t)cc * S_];
    unsigned su = *(const unsigned*)&pwb[(size_t)(cc + 256) * S_];
    float2 xv = *(const float2*)&xb[(size_t)cc * S_];
    float pv0 = bf2f((unsigned short)(pu & 0xffffu));
    float pv1 = bf2f((unsigned short)(pu >> 16));
    float sv0 = bf2f((unsigned short)(su & 0xffffu));
    float sv1 = bf2f((unsigned short)(su >> 16));
    float sc0 = (pv0 - mu0) * rs0 * ga + be;
    float sc1 = (pv1 - mu1) * rs1 * ga + be;
    float sh0 = (sv0 - mu0) * rs0 * gs + bs;
    float sh1 = (sv1 - mu1) * rs1 * gs + bs;
    float2 o;
    o.x = sh0 + xv.x * sc0;
    o.y = sh1 + xv.y * sc1;
    *(float2*)&ob[(size_t)cc * S_] = o;
  }
}

extern "C" void kernel_launch(void* const* d_in, const int* in_sizes, int n_in,
                              void* d_out, int out_size, void* d_ws, size_t ws_size,
                              hipStream_t stream) {
  const float* x = (const float*)d_in[0];
  const float* w_in = (const float*)d_in[1];
  const float* b_in = (const float*)d_in[2];
  const float* ss = (const float*)d_in[3];
  const float* w_dw = (const float*)d_in[4];
  const float* w_pw = (const float*)d_in[5];
  const float* gamma = (const float*)d_in[6];
  const float* beta = (const float*)d_in[7];
  float* out = (float*)d_out;
  char* ws = (char*)d_ws;

  unsigned short* xT = (unsigned short*)(ws + 0);           // 2,359,296
  unsigned short* w_inb = (unsigned short*)(ws + 2359296);  // 786,432
  unsigned short* w_pwb = (unsigned short*)(ws + 3145728);  // 524,288
  unsigned char* qn = (unsigned char*)(ws + 3670016);       // 2,359,296 fp8 [bh][p][64]
  unsigned char* kn = (unsigned char*)(ws + 6029312);       // 2,359,296 fp8 [bh][p][64]
  unsigned short* vT = (unsigned short*)(ws + 8388608);     // 4,718,592 bf16 [bh][d][p]
  unsigned short* dwb = (unsigned short*)(ws + 13107200);   // 4,718,592 bf16
  float* lp = (float*)(ws + 17825792);                      // 589,824  [4][16][2304] fp32
  unsigned short* attnp = (unsigned short*)(ws + 18415616); // bf16 [4][16][2304][64] = 18,874,368
  unsigned short* pw = (unsigned short*)(ws + 37289984);    // bf16 [2][512][2304] = 4,718,592

  k_prep<<<2848, 256, 0, stream>>>(x, w_in, w_pw, xT, w_inb, w_pwb);
  k_gemm_qkv<<<dim3(18, 24, 2), 256, 0, stream>>>(w_inb, xT, b_in, ss, qn, kn, vT);
  k_attn<<<dim3(16, 18, 4), 256, 0, stream>>>(qn, kn, vT, attnp, lp);
  k_dwconv<<<dim3(16, 576), 256, 0, stream>>>(attnp, lp, w_dw, dwb);
  k_gemm2<<<dim3(36, 8, 2), 128, 0, stream>>>(w_pwb, dwb, pw, INNER_, S_, INNER_);
  k_ln_final<<<dim3(144, 2), 256, 0, stream>>>(pw, gamma, beta, x, out);
}

// Round 18
// 151.298 us; speedup vs baseline: 1.1762x; 1.0115x over previous
//
#include <hip/hip_runtime.h>

#define B_ 2
#define C_ 256
#define S_ 2304
#define DH_ 64
#define O3_ 1536
#define INNER_ 512
#define LOGSMAX 4.605170185988092f
#define LOG2E 1.4426950408889634f

typedef __attribute__((ext_vector_type(8))) short short8;
typedef __attribute__((ext_vector_type(4))) float f32x4;
typedef __attribute__((ext_vector_type(16))) float f32x16;
typedef __attribute__((ext_vector_type(4))) unsigned short us4;
typedef __attribute__((ext_vector_type(4))) unsigned u32x4;
typedef __bf16 bf16x8 __attribute__((ext_vector_type(8)));

__device__ __forceinline__ unsigned short f2bf(float f) {
  unsigned u = __builtin_bit_cast(unsigned, f);
  u += 0x7FFFu + ((u >> 16) & 1u);
  return (unsigned short)(u >> 16);
}
__device__ __forceinline__ float bf2f(unsigned short h) {
  return __builtin_bit_cast(float, (unsigned)h << 16);
}
__device__ __forceinline__ bf16x8 as_bf(short8 v) {
  return __builtin_bit_cast(bf16x8, v);
}
__device__ __forceinline__ float fexp2(float x) {
#if __has_builtin(__builtin_amdgcn_exp2f)
  return __builtin_amdgcn_exp2f(x);
#else
  return __expf(x * 0.6931471805599453f);
#endif
}
__device__ __forceinline__ float frcp(float x) {
#if __has_builtin(__builtin_amdgcn_rcpf)
  return __builtin_amdgcn_rcpf(x);
#else
  return 1.f / x;
#endif
}
// pack hi16 of two fp32 bit-patterns: (hi16(b)<<16)|hi16(a) — 1 v_perm_b32
__device__ __forceinline__ unsigned pack_hi16(unsigned b, unsigned a) {
  return __builtin_amdgcn_perm(b, a, 0x07060302u);
}
// half-up bf16 pair pack: dword low = bf16(a), high = bf16(b)
__device__ __forceinline__ unsigned pk2(float a, float b) {
  unsigned ua = __builtin_bit_cast(unsigned, a) + 0x8000u;
  unsigned ub = __builtin_bit_cast(unsigned, b) + 0x8000u;
  return pack_hi16(ub, ua);
}

// ---------------- K0: fused prep: x transpose + both weight converts (x4 vectorized) ----------------
__global__ __launch_bounds__(256) void k_prep(const float* __restrict__ x,
                                              const float* __restrict__ w_in,
                                              const float* __restrict__ w_pw,
                                              unsigned short* __restrict__ xT,
                                              unsigned short* __restrict__ w_inb,
                                              unsigned short* __restrict__ w_pwb) {
  __shared__ float tile[64][65];
  int blk = blockIdx.x;
  int t = threadIdx.x;
  if (blk < 288) {  // transpose x [b][c][p] -> xT [b][p][c] bf16
    int p0 = (blk % 36) * 64, c0 = ((blk / 36) % 4) * 64, b = blk / 144;
    const float* xb = x + (size_t)b * C_ * S_;
#pragma unroll
    for (int i = 0; i < 16; i++) {
      int c = i * 4 + (t >> 6);
      int p = t & 63;
      tile[c][p] = xb[(size_t)(c0 + c) * S_ + p0 + p];
    }
    __syncthreads();
    unsigned short* xTb = xT + (size_t)b * S_ * C_;
#pragma unroll
    for (int i = 0; i < 16; i++) {
      int p = i * 4 + (t >> 6);
      int c = t & 63;
      xTb[(size_t)(p0 + p) * C_ + c0 + c] = f2bf(tile[c][p]);
    }
  } else if (blk < 288 + 384) {  // w_in: 393216 elems, 4/thread
    int i = ((blk - 288) * 256 + t) * 4;
    f32x4 f = *(const f32x4*)&w_in[i];
    us4 o = {f2bf(f[0]), f2bf(f[1]), f2bf(f[2]), f2bf(f[3])};
    *(us4*)&w_inb[i] = o;
  } else {  // w_pw: 262144 elems, 4/thread
    int i = ((blk - 672) * 256 + t) * 4;
    f32x4 f = *(const f32x4*)&w_pw[i];
    us4 o = {f2bf(f[0]), f2bf(f[1]), f2bf(f[2]), f2bf(f[3])};
    *(us4*)&w_pwb[i] = o;
  }
}

// ---------------- K1: proj_in GEMM with fused bias + l2norm + scale epilogue ----------------
// 64x128 tile; M-tile 64 == one (head, q/k/v-seg) channel group.
// Writes qn/kn fp8 [bh][p][64] (scale*log2e folded into q), vT bf16 [bh][d][p] via LDS retile.
__global__ __launch_bounds__(256) void k_gemm_qkv(const unsigned short* __restrict__ A,
                                                  const unsigned short* __restrict__ BT,
                                                  const float* __restrict__ b_in,
                                                  const float* __restrict__ ss,
                                                  unsigned char* __restrict__ qn,
                                                  unsigned char* __restrict__ kn,
                                                  unsigned short* __restrict__ vT) {
  __shared__ __align__(16) unsigned short smem[64 * 72 + 128 * 72];
  unsigned short (*As)[72] = (unsigned short(*)[72])smem;
  unsigned short (*Bs)[72] = (unsigned short(*)[72])(smem + 64 * 72);
  int t = threadIdx.x;
  int lane = t & 63, wv = t >> 6;
  int quad = lane >> 4, r15 = lane & 15;
  int by = blockIdx.y;
  int m0 = by * 64, n0 = blockIdx.x * 128;
  int b = blockIdx.z;
  const unsigned short* BTb = BT + (size_t)b * S_ * C_;

  f32x4 acc[4][2] = {};

  int srA = t >> 2, scA = (t & 3) * 16;
  int srB = t >> 1, scB = (t & 1) * 32;
  const unsigned short* ag = A + (size_t)(m0 + srA) * C_ + scA;
  const unsigned short* bg = BTb + (size_t)(n0 + srB) * C_ + scB;

  for (int k0 = 0; k0 < C_; k0 += 64) {
    short8 a0 = *(const short8*)(ag + k0);
    short8 a1 = *(const short8*)(ag + k0 + 8);
    short8 b0 = *(const short8*)(bg + k0);
    short8 b1 = *(const short8*)(bg + k0 + 8);
    short8 b2 = *(const short8*)(bg + k0 + 16);
    short8 b3 = *(const short8*)(bg + k0 + 24);
    __syncthreads();
    *(short8*)&As[srA][scA] = a0;
    *(short8*)&As[srA][scA + 8] = a1;
    *(short8*)&Bs[srB][scB] = b0;
    *(short8*)&Bs[srB][scB + 8] = b1;
    *(short8*)&Bs[srB][scB + 16] = b2;
    *(short8*)&Bs[srB][scB + 24] = b3;
    __syncthreads();
#pragma unroll
    for (int ks = 0; ks < 2; ks++) {
      short8 af[4], bfr[2];
#pragma unroll
      for (int i = 0; i < 4; i++) af[i] = *(const short8*)&As[i * 16 + r15][ks * 32 + quad * 8];
#pragma unroll
      for (int j = 0; j < 2; j++) bfr[j] = *(const short8*)&Bs[wv * 32 + j * 16 + r15][ks * 32 + quad * 8];
#pragma unroll
      for (int i = 0; i < 4; i++)
#pragma unroll
        for (int j = 0; j < 2; j++)
          acc[i][j] = __builtin_amdgcn_mfma_f32_16x16x32_bf16(as_bf(af[i]), as_bf(bfr[j]), acc[i][j], 0, 0, 0);
    }
  }

  // epilogue: bias add, per-position l2norm (q/k) -> fp8; v -> vT bf16 [d][p] via LDS
  int h = by / 3, seg = by - h * 3;
  int bh = b * 8 + h;
  f32x4 bi[4];
#pragma unroll
  for (int i = 0; i < 4; i++) bi[i] = *(const f32x4*)&b_in[m0 + i * 16 + quad * 4];
  float bv[4][2][4];
  float ssq0 = 0.f, ssq1 = 0.f;
#pragma unroll
  for (int i = 0; i < 4; i++)
#pragma unroll
    for (int rr = 0; rr < 4; rr++) {
      float v0 = acc[i][0][rr] + bi[i][rr];
      float v1 = acc[i][1][rr] + bi[i][rr];
      bv[i][0][rr] = v0;
      bv[i][1][rr] = v1;
      ssq0 += v0 * v0;
      ssq1 += v1 * v1;
    }
  if (seg < 2) {
    float sc = (seg == 0) ? __expf(fminf(ss[h], LOGSMAX)) * LOG2E : 1.f;
    ssq0 += __shfl_xor(ssq0, 16);
    ssq0 += __shfl_xor(ssq0, 32);
    ssq1 += __shfl_xor(ssq1, 16);
    ssq1 += __shfl_xor(ssq1, 32);
    float inv0 = sc / fmaxf(sqrtf(ssq0), 1e-12f);
    float inv1 = sc / fmaxf(sqrtf(ssq1), 1e-12f);
    unsigned char* dst = (seg == 0 ? qn : kn) + (size_t)bh * S_ * DH_;
#pragma unroll
    for (int i = 0; i < 4; i++)
#pragma unroll
      for (int j = 0; j < 2; j++) {
        float iv = j ? inv1 : inv0;
        int pk = __builtin_amdgcn_cvt_pk_fp8_f32(bv[i][j][0] * iv, bv[i][j][1] * iv, 0, false);
        pk = __builtin_amdgcn_cvt_pk_fp8_f32(bv[i][j][2] * iv, bv[i][j][3] * iv, pk, true);
        int p = n0 + wv * 32 + j * 16 + r15;
        *(int*)&dst[(size_t)p * DH_ + i * 16 + quad * 4] = pk;
      }
  } else {
    // retile v through LDS: [d][p] tile (stride 132), then coalesced 16B stores
    __syncthreads();
    unsigned short* vt = smem;
#pragma unroll
    for (int i = 0; i < 4; i++)
#pragma unroll
      for (int j = 0; j < 2; j++) {
        int pcol = wv * 32 + j * 16 + r15;
#pragma unroll
        for (int rr = 0; rr < 4; rr++) {
          int d = i * 16 + quad * 4 + rr;
          vt[d * 132 + pcol] = f2bf(bv[i][j][rr]);
        }
      }
    __syncthreads();
    unsigned short* dst = vT + (size_t)bh * DH_ * S_;
    int dr = t >> 2, pc = (t & 3) * 32;
#pragma unroll
    for (int s2 = 0; s2 < 4; s2++) {
      short8 v8 = *(const short8*)&vt[dr * 132 + pc + s2 * 8];
      *(short8*)&dst[(size_t)dr * S_ + n0 + pc + s2 * 8] = v8;
    }
  }
}

// ---------------- K5: pw GEMM, 64x64 tile, 2 waves, bf16 output ----------------
__global__ __launch_bounds__(128) void k_gemm2(const unsigned short* __restrict__ A,
                                               const unsigned short* __restrict__ BT,
                                               unsigned short* __restrict__ outp,
                                               int M, int N, int K) {
  __shared__ __align__(16) unsigned short As[64][72];
  __shared__ __align__(16) unsigned short Bs[64][72];
  int t = threadIdx.x;
  int lane = t & 63, wv = t >> 6;
  int quad = lane >> 4, r15 = lane & 15;
  int m0 = blockIdx.y * 64, n0 = blockIdx.x * 64;
  int b = blockIdx.z;
  const unsigned short* BTb = BT + (size_t)b * N * K;

  f32x4 acc[4][2] = {};

  int sr = t >> 1, sc = (t & 1) * 32;
  const unsigned short* ag = A + (size_t)(m0 + sr) * K + sc;
  const unsigned short* bg = BTb + (size_t)(n0 + sr) * K + sc;

  for (int k0 = 0; k0 < K; k0 += 64) {
    short8 a0 = *(const short8*)(ag + k0);
    short8 a1 = *(const short8*)(ag + k0 + 8);
    short8 a2 = *(const short8*)(ag + k0 + 16);
    short8 a3 = *(const short8*)(ag + k0 + 24);
    short8 b0 = *(const short8*)(bg + k0);
    short8 b1 = *(const short8*)(bg + k0 + 8);
    short8 b2 = *(const short8*)(bg + k0 + 16);
    short8 b3 = *(const short8*)(bg + k0 + 24);
    __syncthreads();
    *(short8*)&As[sr][sc] = a0;
    *(short8*)&As[sr][sc + 8] = a1;
    *(short8*)&As[sr][sc + 16] = a2;
    *(short8*)&As[sr][sc + 24] = a3;
    *(short8*)&Bs[sr][sc] = b0;
    *(short8*)&Bs[sr][sc + 8] = b1;
    *(short8*)&Bs[sr][sc + 16] = b2;
    *(short8*)&Bs[sr][sc + 24] = b3;
    __syncthreads();
#pragma unroll
    for (int ks = 0; ks < 2; ks++) {
      short8 af[4], bfr[2];
#pragma unroll
      for (int i = 0; i < 4; i++) af[i] = *(const short8*)&As[i * 16 + r15][ks * 32 + quad * 8];
#pragma unroll
      for (int j = 0; j < 2; j++) bfr[j] = *(const short8*)&Bs[wv * 32 + j * 16 + r15][ks * 32 + quad * 8];
#pragma unroll
      for (int i = 0; i < 4; i++)
#pragma unroll
        for (int j = 0; j < 2; j++)
          acc[i][j] = __builtin_amdgcn_mfma_f32_16x16x32_bf16(as_bf(af[i]), as_bf(bfr[j]), acc[i][j], 0, 0, 0);
    }
  }
  unsigned short* Cb = outp + (size_t)b * M * N;
#pragma unroll
  for (int i = 0; i < 4; i++)
#pragma unroll
    for (int j = 0; j < 2; j++)
#pragma unroll
      for (int rr = 0; rr < 4; rr++) {
        int row = m0 + i * 16 + quad * 4 + rr;
        int col = n0 + wv * 32 + j * 16 + r15;
        Cb[(size_t)row * N + col] = f2bf(acc[i][j][rr]);
      }
}

// ---------------- K3: hybrid attention, double-buffered LDS (1 barrier/iter), shiftless ----------------
// Q/K fp8 (S^T MFMA), P/V bf16 (O MFMA). 4 waves x 32q, split-K x4.
// Grid (bh, qtile, split): bh fastest -> XCD = bh%8 pinned.
__global__ __launch_bounds__(256) void k_attn(const unsigned char* __restrict__ qn,
                                              const unsigned char* __restrict__ kn,
                                              const unsigned short* __restrict__ vT,
                                              unsigned short* __restrict__ attnp,
                                              float* __restrict__ lp) {
  __shared__ __align__(16) unsigned char Ks[2][64][72];    // [buf][key][d] fp8
  __shared__ __align__(16) unsigned short Vs[2][64][72];   // [buf][d][key] bf16
  int t = threadIdx.x;
  int w = t >> 6;
  int lane = t & 63;
  int l31 = lane & 31, hi = lane >> 5;
  int bh = blockIdx.x;
  int q0 = blockIdx.y * 128 + w * 32;
  int split = blockIdx.z;
  int ktbase = split * 9;
  const unsigned char* qb = qn + (size_t)bh * S_ * DH_;
  const unsigned char* kb = kn + (size_t)bh * S_ * DH_;
  const unsigned short* vb = vT + (size_t)bh * DH_ * S_;

  // Q as fp8 B-fragment: n=query=l31, k(d) = ks*16 + hi*8 + j
  const unsigned char* qrow = qb + (size_t)(q0 + l31) * DH_ + hi * 8;
  long qf[4];
#pragma unroll
  for (int ks = 0; ks < 4; ks++) qf[ks] = *(const long*)(qrow + ks * 16);

  const f32x16 z16 = {};
  f32x16 O0 = z16, O1 = z16;
  float l_part = 0.f;

  // staging: K 64key x 64B fp8 (16B/thread), V 64d x 64key bf16 (32B/thread)
  int srow = t >> 2;
  int scolK = (t & 3) * 16;     // bytes
  int scolV = (t & 3) * 16;     // shorts
  const unsigned char* kg = kb + ((size_t)(ktbase * 64) + srow) * DH_ + scolK;
  const unsigned short* vg = vb + (size_t)srow * S_ + ktbase * 64 + scolV;

  // tile 0 -> buf0; prefetch tile 1 to regs; single barrier
  {
    uint4 k0 = *(const uint4*)kg;
    short8 v0a = *(const short8*)vg;
    short8 v0b = *(const short8*)(vg + 8);
    *(uint4*)&Ks[0][srow][scolK] = k0;
    *(short8*)&Vs[0][srow][scolV] = v0a;
    *(short8*)&Vs[0][srow][scolV + 8] = v0b;
  }
  uint4 kr = *(const uint4*)(kg + (size_t)64 * DH_);
  short8 vr0 = *(const short8*)(vg + 64);
  short8 vr1 = *(const short8*)(vg + 64 + 8);
  __syncthreads();

  for (int i = 0; i < 9; i++) {
    int cur = i & 1;
    if (i < 8) {
      // write prefetched tile i+1 into the other buffer (its last readers finished at iter i-1)
      *(uint4*)&Ks[cur ^ 1][srow][scolK] = kr;
      *(short8*)&Vs[cur ^ 1][srow][scolV] = vr0;
      *(short8*)&Vs[cur ^ 1][srow][scolV + 8] = vr1;
      if (i < 7) {  // prefetch tile i+2
        kr = *(const uint4*)(kg + (size_t)(i + 2) * 64 * DH_);
        vr0 = *(const short8*)(vg + (i + 2) * 64);
        vr1 = *(const short8*)(vg + (i + 2) * 64 + 8);
      }
    }
    // S^T = K Q^T : A = K fp8 frags (m=key), B = Q fp8 regs (n=query)
    f32x16 sc0, sc1;
    {
      long a0 = *(const long*)&Ks[cur][l31][hi * 8];
      long a1 = *(const long*)&Ks[cur][32 + l31][hi * 8];
      sc0 = __builtin_amdgcn_mfma_f32_32x32x16_fp8_fp8(a0, qf[0], z16, 0, 0, 0);
      sc1 = __builtin_amdgcn_mfma_f32_32x32x16_fp8_fp8(a1, qf[0], z16, 0, 0, 0);
    }
#pragma unroll
    for (int ks = 1; ks < 4; ks++) {
      long a0 = *(const long*)&Ks[cur][l31][ks * 16 + hi * 8];
      long a1 = *(const long*)&Ks[cur][32 + l31][ks * 16 + hi * 8];
      sc0 = __builtin_amdgcn_mfma_f32_32x32x16_fp8_fp8(a0, qf[ks], sc0, 0, 0, 0);
      sc1 = __builtin_amdgcn_mfma_f32_32x32x16_fp8_fp8(a1, qf[ks], sc1, 0, 0, 0);
    }
    // shiftless exp2 numerator (|s| <= 0.26; constant shift cancels in O/l);
    // pack to bf16 dwords in C-layout; relayout to B-frag via shfl_xor(32).
#pragma unroll
    for (int mt = 0; mt < 2; mt++) {
      const f32x16& s = mt ? sc1 : sc0;
      unsigned pk[8];
      float lsum = 0.f;
#pragma unroll
      for (int g2 = 0; g2 < 4; g2++) {
        float e0 = fexp2(s[g2 * 4 + 0]);
        float e1 = fexp2(s[g2 * 4 + 1]);
        float e2 = fexp2(s[g2 * 4 + 2]);
        float e3 = fexp2(s[g2 * 4 + 3]);
        lsum += (e0 + e1) + (e2 + e3);
        pk[2 * g2] = pk2(e0, e1);
        pk[2 * g2 + 1] = pk2(e2, e3);
      }
      l_part += lsum;
#pragma unroll
      for (int half = 0; half < 2; half++) {
        int gb = half * 4;
        unsigned ya = hi ? pk[gb + 0] : pk[gb + 2];
        unsigned yb = hi ? pk[gb + 1] : pk[gb + 3];
        unsigned ra = __shfl_xor(ya, 32);
        unsigned rb = __shfl_xor(yb, 32);
        u32x4 fd;
        fd[0] = hi ? ra : pk[gb + 0];
        fd[1] = hi ? rb : pk[gb + 1];
        fd[2] = hi ? pk[gb + 2] : ra;
        fd[3] = hi ? pk[gb + 3] : rb;
        short8 pb = __builtin_bit_cast(short8, fd);
        int ks = mt * 2 + half;
        short8 va0 = *(const short8*)&Vs[cur][l31][ks * 16 + hi * 8];
        short8 va1 = *(const short8*)&Vs[cur][32 + l31][ks * 16 + hi * 8];
        O0 = __builtin_amdgcn_mfma_f32_32x32x16_bf16(as_bf(va0), as_bf(pb), O0, 0, 0, 0);
        O1 = __builtin_amdgcn_mfma_f32_32x32x16_bf16(as_bf(va1), as_bf(pb), O1, 0, 0, 0);
      }
    }
    __syncthreads();
  }
  float l = l_part + __shfl_xor(l_part, 32);
  if (hi == 0) lp[((size_t)(split * 16 + bh)) * S_ + q0 + l31] = l;
  unsigned short* orow = attnp + (((size_t)(split * 16 + bh)) * S_ + q0 + l31) * DH_;
#pragma unroll
  for (int mt = 0; mt < 2; mt++) {
    const f32x16& O = mt ? O1 : O0;
#pragma unroll
    for (int g = 0; g < 4; g++) {
      us4 o4 = {f2bf(O[g * 4 + 0]), f2bf(O[g * 4 + 1]), f2bf(O[g * 4 + 2]), f2bf(O[g * 4 + 3])};
      *(us4*)&orow[mt * 32 + g * 8 + hi * 4] = o4;
    }
  }
}

// ---------------- K4: depthwise 3x3, LDS-shared 3x6 combined stencil tile ----------------
// Grid (bh, pblk): bh fastest -> XCD pinned per bh.
__global__ __launch_bounds__(256) void k_dwconv(const unsigned short* __restrict__ attnp,
                                                const float* __restrict__ lp,
                                                const float* __restrict__ w_dw,
                                                unsigned short* __restrict__ dwb) {
  __shared__ float sc[3][6][64];
  int t = threadIdx.x;
  int d = t & 63;
  int wv = t >> 6;
  int bh = blockIdx.x;
  int b = bh >> 3, h = bh & 7;
  int p0 = blockIdx.y * 4;
  int x0 = p0 % 48, y0 = p0 / 48;
  const unsigned short* a0 = attnp + (size_t)bh * S_ * DH_ + d;
  const unsigned short* a1 = attnp + ((size_t)(16 + bh)) * S_ * DH_ + d;
  const unsigned short* a2 = attnp + ((size_t)(32 + bh)) * S_ * DH_ + d;
  const unsigned short* a3 = attnp + ((size_t)(48 + bh)) * S_ * DH_ + d;
  const float* l0 = lp + (size_t)bh * S_;
  const float* l1 = lp + (size_t)(16 + bh) * S_;
  const float* l2 = lp + (size_t)(32 + bh) * S_;
  const float* l3 = lp + (size_t)(48 + bh) * S_;
  for (int i = wv; i < 18; i += 4) {
    int ry = i / 6, cx = i - ry * 6;
    int y2 = y0 + ry - 1, x2 = x0 + cx - 1;
    float val = 0.f;
    if (y2 >= 0 && y2 < 48 && x2 >= 0 && x2 < 48) {
      int p2 = y2 * 48 + x2;  // wave-uniform
      float rl = frcp(l0[p2] + l1[p2] + l2[p2] + l3[p2]);
      val = (bf2f(a0[(size_t)p2 * DH_]) + bf2f(a1[(size_t)p2 * DH_]) +
             bf2f(a2[(size_t)p2 * DH_]) + bf2f(a3[(size_t)p2 * DH_])) * rl;
    }
    sc[ry][cx][d] = val;
  }
  __syncthreads();
  int ch = h * 64 + d;
  float w[9];
#pragma unroll
  for (int i = 0; i < 9; i++) w[i] = w_dw[ch * 9 + i];
  float acc = 0.f;
#pragma unroll
  for (int dy = 0; dy < 3; dy++)
#pragma unroll
    for (int dx = 0; dx < 3; dx++)
      acc += sc[dy][wv + dx][d] * w[dy * 3 + dx];
  dwb[((size_t)b * S_ + p0 + wv) * INNER_ + ch] = f2bf(acc);
}

// ---------------- K6: channel LN + scales/shifts + final (pw bf16) ----------------
__global__ __launch_bounds__(256) void k_ln_final(const unsigned short* __restrict__ pw,
                                                  const float* __restrict__ gamma,
                                                  const float* __restrict__ beta,
                                                  const float* __restrict__ x,
                                                  float* __restrict__ out) {
  __shared__ float s_s0[32][8], s_s1[32][8], s_q0[32][8], s_q1[32][8];
  int t = threadIdx.x;
  int pl = t & 7, g = t >> 3;
  int b = blockIdx.y;
  int p = blockIdx.x * 16 + pl * 2;
  const unsigned short* pwb = pw + (size_t)b * INNER_ * S_ + p;
  float s0 = 0.f, s1 = 0.f, q0 = 0.f, q1 = 0.f;
#pragma unroll
  for (int j = 0; j < 16; j++) {
    unsigned u = *(const unsigned*)&pwb[(size_t)(g * 16 + j) * S_];
    float vx = bf2f((unsigned short)(u & 0xffffu));
    float vy = bf2f((unsigned short)(u >> 16));
    s0 += vx; s1 += vy;
    q0 += vx * vx; q1 += vy * vy;
  }
  s_s0[g][pl] = s0; s_s1[g][pl] = s1;
  s_q0[g][pl] = q0; s_q1[g][pl] = q1;
  __syncthreads();
  float t0 = 0.f, t1 = 0.f, u0 = 0.f, u1 = 0.f;
#pragma unroll
  for (int i = 0; i < 32; i++) {
    t0 += s_s0[i][pl]; t1 += s_s1[i][pl];
    u0 += s_q0[i][pl]; u1 += s_q1[i][pl];
  }
  float mu0 = t0 * (1.f / 512.f), mu1 = t1 * (1.f / 512.f);
  float rs0 = rsqrtf(u0 * (1.f / 512.f) - mu0 * mu0 + 1e-5f);
  float rs1 = rsqrtf(u1 * (1.f / 512.f) - mu1 * mu1 + 1e-5f);
  const float* xb = x + (size_t)b * C_ * S_ + p;
  float* ob = out + (size_t)b * C_ * S_ + p;
#pragma unroll
  for (int j = 0; j < 8; j++) {
    int cc = g * 8 + j;
    float ga = gamma[cc], be = beta[cc];
    float gs = gamma[cc + 256], bs = beta[cc + 256];
    unsigned pu = *(const unsigned*)&pwb[(size_t)cc * S_];
    unsigned su = *(const unsigned*)&pwb[(size_t)(cc + 256) * S_];
    float2 xv = *(const float2*)&xb[(size_t)cc * S_];
    float pv0 = bf2f((unsigned short)(pu & 0xffffu));
    float pv1 = bf2f((unsigned short)(pu >> 16));
    float sv0 = bf2f((unsigned short)(su & 0xffffu));
    float sv1 = bf2f((unsigned short)(su >> 16));
    float sc0 = (pv0 - mu0) * rs0 * ga + be;
    float sc1 = (pv1 - mu1) * rs1 * ga + be;
    float sh0 = (sv0 - mu0) * rs0 * gs + bs;
    float sh1 = (sv1 - mu1) * rs1 * gs + bs;
    float2 o;
    o.x = sh0 + xv.x * sc0;
    o.y = sh1 + xv.y * sc1;
    *(float2*)&ob[(size_t)cc * S_] = o;
  }
}

extern "C" void kernel_launch(void* const* d_in, const int* in_sizes, int n_in,
                              void* d_out, int out_size, void* d_ws, size_t ws_size,
                              hipStream_t stream) {
  const float* x = (const float*)d_in[0];
  const float* w_in = (const float*)d_in[1];
  const float* b_in = (const float*)d_in[2];
  const float* ss = (const float*)d_in[3];
  const float* w_dw = (const float*)d_in[4];
  const float* w_pw = (const float*)d_in[5];
  const float* gamma = (const float*)d_in[6];
  const float* beta = (const float*)d_in[7];
  float* out = (float*)d_out;
  char* ws = (char*)d_ws;

  unsigned short* xT = (unsigned short*)(ws + 0);           // 2,359,296
  unsigned short* w_inb = (unsigned short*)(ws + 2359296);  // 786,432
  unsigned short* w_pwb = (unsigned short*)(ws + 3145728);  // 524,288
  unsigned char* qn = (unsigned char*)(ws + 3670016);       // 2,359,296 fp8 [bh][p][64]
  unsigned char* kn = (unsigned char*)(ws + 6029312);       // 2,359,296 fp8 [bh][p][64]
  unsigned short* vT = (unsigned short*)(ws + 8388608);     // 4,718,592 bf16 [bh][d][p]
  unsigned short* dwb = (unsigned short*)(ws + 13107200);   // 4,718,592 bf16
  float* lp = (float*)(ws + 17825792);                      // 589,824  [4][16][2304] fp32
  unsigned short* attnp = (unsigned short*)(ws + 18415616); // bf16 [4][16][2304][64] = 18,874,368
  unsigned short* pw = (unsigned short*)(ws + 37289984);    // bf16 [2][512][2304] = 4,718,592

  k_prep<<<928, 256, 0, stream>>>(x, w_in, w_pw, xT, w_inb, w_pwb);
  k_gemm_qkv<<<dim3(18, 24, 2), 256, 0, stream>>>(w_inb, xT, b_in, ss, qn, kn, vT);
  k_attn<<<dim3(16, 18, 4), 256, 0, stream>>>(qn, kn, vT, attnp, lp);
  k_dwconv<<<dim3(16, 576), 256, 0, stream>>>(attnp, lp, w_dw, dwb);
  k_gemm2<<<dim3(36, 8, 2), 128, 0, stream>>>(w_pwb, dwb, pw, INNER_, S_, INNER_);
  k_ln_final<<<dim3(144, 2), 256, 0, stream>>>(pw, gamma, beta, x, out);
}